// Round 2
// baseline (1368.451 us; speedup 1.0000x reference)
//
#include <hip/hip_runtime.h>
#include <hip/hip_bf16.h>
#include <stdint.h>
#include <stddef.h>

// Problem constants (from reference)
#define N_NODES  20000
#define N_EDGES  320000
#define N_GRAPH  64
#define F_IN     128
#define E_DIM    32
#define H_DIM    300
#define HID_DIM  600
#define DL_DIM   256
#define DOUT_DIM 128
#define BN_INV_F 0.9999950000374997f
#define EPS_MSG  1e-7f

// ---------------------------------------------------------------------------
// Generic tiled fp32 GEMM: C[M,N] = epilogue(A[M,K] @ B[K,N])
// 64x64 tile, BK=16, 256 threads, 4x4 per thread. Requires K%4==0, N%4==0.
// ---------------------------------------------------------------------------
#define TS 64
#define KS 16

template<bool HAS_BIAS, bool RELU, bool BN>
__global__ __launch_bounds__(256)
void gemm_ep(const float* __restrict__ A, const float* __restrict__ B,
             const float* __restrict__ bias, const float* __restrict__ gamma,
             const float* __restrict__ beta, float* __restrict__ C,
             int M, int N, int K)
{
    __shared__ float As[KS][TS + 4];
    __shared__ float Bs[KS][TS + 4];
    const int tid = threadIdx.x;
    const int bm = blockIdx.y * TS;
    const int bn = blockIdx.x * TS;
    const int tm = (tid / 16) * 4;
    const int tn = (tid % 16) * 4;

    float acc[4][4] = {};

    for (int k0 = 0; k0 < K; k0 += KS) {
        {
            int idx = tid * 4;
            int i = idx / KS;          // tile row 0..63
            int kk = idx % KS;         // 0,4,8,12
            int gm = bm + i, gk = k0 + kk;
            float4 v = make_float4(0.f, 0.f, 0.f, 0.f);
            if (gm < M && gk < K)
                v = *(const float4*)(A + (size_t)gm * K + gk);
            As[kk + 0][i] = v.x; As[kk + 1][i] = v.y;
            As[kk + 2][i] = v.z; As[kk + 3][i] = v.w;
        }
        {
            int idx = tid * 4;
            int kk = idx / TS;         // 0..15
            int j  = idx % TS;         // 0,4,..,60
            int gk = k0 + kk, gn = bn + j;
            float4 v = make_float4(0.f, 0.f, 0.f, 0.f);
            if (gk < K && gn < N)
                v = *(const float4*)(B + (size_t)gk * N + gn);
            *(float4*)&Bs[kk][j] = v;
        }
        __syncthreads();
        #pragma unroll
        for (int kk = 0; kk < KS; ++kk) {
            float4 a = *(const float4*)&As[kk][tm];
            float4 b = *(const float4*)&Bs[kk][tn];
            acc[0][0] += a.x * b.x; acc[0][1] += a.x * b.y;
            acc[0][2] += a.x * b.z; acc[0][3] += a.x * b.w;
            acc[1][0] += a.y * b.x; acc[1][1] += a.y * b.y;
            acc[1][2] += a.y * b.z; acc[1][3] += a.y * b.w;
            acc[2][0] += a.z * b.x; acc[2][1] += a.z * b.y;
            acc[2][2] += a.z * b.z; acc[2][3] += a.z * b.w;
            acc[3][0] += a.w * b.x; acc[3][1] += a.w * b.y;
            acc[3][2] += a.w * b.z; acc[3][3] += a.w * b.w;
        }
        __syncthreads();
    }

    #pragma unroll
    for (int i = 0; i < 4; ++i) {
        int gm = bm + tm + i;
        if (gm >= M) continue;
        #pragma unroll
        for (int j = 0; j < 4; ++j) {
            int gn = bn + tn + j;
            if (gn >= N) continue;
            float v = acc[i][j];
            if (HAS_BIAS) v += bias[gn];
            if (RELU)     v = fmaxf(v, 0.f);
            if (BN)       v = v * (BN_INV_F * gamma[gn]) + beta[gn];
            C[(size_t)gm * N + gn] = v;
        }
    }
}

// ---------------------------------------------------------------------------
// CSR build: histogram of dst, exclusive scan, scatter edge ids.
// ---------------------------------------------------------------------------
__global__ __launch_bounds__(256)
void hist_kernel(const int* __restrict__ ei, int* __restrict__ counts)
{
    for (int e = blockIdx.x * 256 + threadIdx.x; e < N_EDGES; e += gridDim.x * 256)
        atomicAdd(&counts[ei[N_EDGES + e]], 1);
}

__global__ __launch_bounds__(256)
void scan_kernel(const int* __restrict__ counts, int* __restrict__ rowptr)
{
    __shared__ int sdata[256];
    __shared__ int running;
    int tid = threadIdx.x;
    if (tid == 0) { running = 0; rowptr[0] = 0; }
    __syncthreads();
    for (int base = 0; base < N_NODES; base += 256) {
        int i = base + tid;
        int v = (i < N_NODES) ? counts[i] : 0;
        sdata[tid] = v;
        __syncthreads();
        #pragma unroll
        for (int off = 1; off < 256; off <<= 1) {
            int t = (tid >= off) ? sdata[tid - off] : 0;
            __syncthreads();
            sdata[tid] += t;
            __syncthreads();
        }
        if (i < N_NODES) rowptr[i + 1] = running + sdata[tid];
        __syncthreads();
        if (tid == 255) running += sdata[255];
        __syncthreads();
    }
}

__global__ __launch_bounds__(256)
void scatter_kernel(const int* __restrict__ ei, const int* __restrict__ rowptr,
                    int* __restrict__ cursor, int* __restrict__ sorted_eid)
{
    for (int e = blockIdx.x * 256 + threadIdx.x; e < N_EDGES; e += gridDim.x * 256) {
        int d = ei[N_EDGES + e];
        int pos = atomicAdd(&cursor[d], 1);
        sorted_eid[rowptr[d] + pos] = e;
    }
}

// ---------------------------------------------------------------------------
// Aggregation: one wave per (node, channel-group). Online softmax in regs.
// e = edge_attr @ W_edge fused: lane keeps its channel's W_edge column (32
// floats) in VGPRs; edge_attr row read via wave-uniform L1-broadcast loads.
// out0 = softmax_agg + xd, written in place over xd.
// ---------------------------------------------------------------------------
__global__ __launch_bounds__(256)
void agg_csr(const float* __restrict__ h, const float* __restrict__ ea,
             const int* __restrict__ ei_src, const int* __restrict__ rowptr,
             const int* __restrict__ sorted_eid, const float* __restrict__ We,
             float* __restrict__ out0 /* holds xd on entry */)
{
    const int g = blockIdx.y;                      // channel group 0..4
    const int lane = threadIdx.x & 63;
    const int c = g * 64 + lane;
    const bool act = c < H_DIM;
    const int cc = act ? c : (H_DIM - 1);          // clamped for safe loads

    float wreg[E_DIM];
    #pragma unroll
    for (int k = 0; k < E_DIM; ++k)
        wreg[k] = We[(size_t)k * H_DIM + cc];

    const int wglobal = blockIdx.x * 4 + (threadIdx.x >> 6);
    const int nwaves = gridDim.x * 4;

    for (int n = wglobal; n < N_NODES; n += nwaves) {
        int beg = rowptr[n], end = rowptr[n + 1];
        float m = -1e30f, den = 0.f, num = 0.f;
        for (int p = beg; p < end; ++p) {
            int e = sorted_eid[p];
            int s = ei_src[e];
            const float4* ear = (const float4*)(ea + (size_t)e * E_DIM);
            float ec = 0.f;
            #pragma unroll
            for (int q = 0; q < 8; ++q) {
                float4 v = ear[q];
                ec += v.x * wreg[4 * q + 0] + v.y * wreg[4 * q + 1]
                    + v.z * wreg[4 * q + 2] + v.w * wreg[4 * q + 3];
            }
            float msg = fmaxf(h[(size_t)s * H_DIM + cc] + ec, 0.f) + EPS_MSG;
            if (msg > m) {
                float r = __expf(m - msg);   // first iter: exp(-huge) = 0
                den *= r; num *= r; m = msg;
            }
            float ex = __expf(msg - m);
            den += ex;
            num += msg * ex;
        }
        float agg = (end > beg) ? num / den : 0.f;
        if (act) {
            size_t idx = (size_t)n * H_DIM + c;
            out0[idx] = agg + out0[idx];
        }
    }
}

// ---------------------------------------------------------------------------
// pooling
// ---------------------------------------------------------------------------
__global__ __launch_bounds__(128)
void pool_kernel(const float* __restrict__ out3, const int* __restrict__ batch,
                 float* __restrict__ pooled, float* __restrict__ cnt)
{
    int n = blockIdx.x;
    int c = threadIdx.x;
    int g = batch[n];
    atomicAdd(&pooled[(size_t)g * DOUT_DIM + c], out3[(size_t)n * DOUT_DIM + c]);
    if (c == 0) atomicAdd(&cnt[g], 1.f);
}

__global__ __launch_bounds__(256)
void finalize_kernel(const float* __restrict__ pooled, const float* __restrict__ cnt,
                     float* __restrict__ out)
{
    int i = blockIdx.x * 256 + threadIdx.x;
    if (i >= N_GRAPH * DOUT_DIM) return;
    out[i] = pooled[i] / fmaxf(cnt[i / DOUT_DIM], 1.f);
}

// ---------------------------------------------------------------------------
extern "C" void kernel_launch(void* const* d_in, const int* in_sizes, int n_in,
                              void* d_out, int out_size, void* d_ws, size_t ws_size,
                              hipStream_t stream)
{
    const float* x      = (const float*)d_in[0];
    const float* ea     = (const float*)d_in[1];
    const int*   eidx   = (const int*)d_in[2];   // [2,E]: row0=src, row1=dst
    const int*   batch  = (const int*)d_in[3];
    const float* W_src  = (const float*)d_in[4];
    const float* W_edge = (const float*)d_in[5];
    const float* W_dst  = (const float*)d_in[6];
    const float* W1     = (const float*)d_in[7];
    const float* b1     = (const float*)d_in[8];
    const float* g1     = (const float*)d_in[9];
    const float* be1    = (const float*)d_in[10];
    const float* W2     = (const float*)d_in[11];
    const float* b2     = (const float*)d_in[12];
    const float* g2     = (const float*)d_in[13];
    const float* be2    = (const float*)d_in[14];
    const float* W3     = (const float*)d_in[15];
    const float* b3     = (const float*)d_in[16];
    const float* L1     = (const float*)d_in[17];
    const float* bl1    = (const float*)d_in[18];
    const float* L2     = (const float*)d_in[19];
    const float* bl2    = (const float*)d_in[20];
    float* out = (float*)d_out;
    char* ws = (char*)d_ws;

    // Workspace layout (bytes) — peak ~97.7 MB
    float* ws_h    = (float*)(ws + 0);           // [N,300] 24MB
    float* ws_xd   = (float*)(ws + 24000000);    // [N,300] xd -> out0 (in place)
    float* ws_b1   = (float*)(ws + 48000000);    // [N,600] 48MB (48M..96M)
    float* ws_b2   = (float*)(ws + 0);           // [N,600] reuse 0..48M
    float* ws_out1 = (float*)(ws + 48000000);    // [N,300] reuse 48..72M
    float* ws_out2 = (float*)(ws + 72000000);    // [N,256] reuse 72..92.5M
    float* ws_out3 = (float*)(ws + 0);           // [N,128] reuse 0..10.3M
    int*   ws_cnts = (int*)  (ws + 96000000);    // [20000]
    int*   ws_curs = (int*)  (ws + 96100000);    // [20000]
    int*   ws_rptr = (int*)  (ws + 96200000);    // [20001]
    int*   ws_sort = (int*)  (ws + 96300000);    // [320000] ints
    float* ws_pool = (float*)(ws + 97600000);    // [64,128]
    float* ws_cnt  = (float*)(ws + 97650000);    // [64]

    hipMemsetAsync(ws_cnts, 0, N_NODES * sizeof(int), stream);
    hipMemsetAsync(ws_curs, 0, N_NODES * sizeof(int), stream);
    hipMemsetAsync(ws_pool, 0, (size_t)N_GRAPH * DOUT_DIM * 4, stream);
    hipMemsetAsync(ws_cnt,  0, N_GRAPH * 4, stream);

    dim3 blk(256);
    auto grid2 = [](int M, int N) { return dim3((N + TS - 1) / TS, (M + TS - 1) / TS); };

    // h = x @ W_src ; xd = x @ W_dst
    gemm_ep<false, false, false><<<grid2(N_NODES, H_DIM), blk, 0, stream>>>(
        x, W_src, nullptr, nullptr, nullptr, ws_h, N_NODES, H_DIM, F_IN);
    gemm_ep<false, false, false><<<grid2(N_NODES, H_DIM), blk, 0, stream>>>(
        x, W_dst, nullptr, nullptr, nullptr, ws_xd, N_NODES, H_DIM, F_IN);

    // CSR build
    hist_kernel<<<512, blk, 0, stream>>>(eidx, ws_cnts);
    scan_kernel<<<1, blk, 0, stream>>>(ws_cnts, ws_rptr);
    scatter_kernel<<<512, blk, 0, stream>>>(eidx, ws_rptr, ws_curs, ws_sort);

    // softmax aggregation + residual (out0 = agg + xd, in place over xd)
    agg_csr<<<dim3(200, 5), blk, 0, stream>>>(
        ws_h, ea, eidx, ws_rptr, ws_sort, W_edge, ws_xd);

    // MLP chain
    gemm_ep<true, true, true><<<grid2(N_NODES, HID_DIM), blk, 0, stream>>>(
        ws_xd, W1, b1, g1, be1, ws_b1, N_NODES, HID_DIM, H_DIM);
    gemm_ep<true, true, true><<<grid2(N_NODES, HID_DIM), blk, 0, stream>>>(
        ws_b1, W2, b2, g2, be2, ws_b2, N_NODES, HID_DIM, HID_DIM);
    gemm_ep<true, false, false><<<grid2(N_NODES, H_DIM), blk, 0, stream>>>(
        ws_b2, W3, b3, nullptr, nullptr, ws_out1, N_NODES, H_DIM, HID_DIM);
    gemm_ep<true, true, false><<<grid2(N_NODES, DL_DIM), blk, 0, stream>>>(
        ws_out1, L1, bl1, nullptr, nullptr, ws_out2, N_NODES, DL_DIM, H_DIM);
    gemm_ep<true, false, false><<<grid2(N_NODES, DOUT_DIM), blk, 0, stream>>>(
        ws_out2, L2, bl2, nullptr, nullptr, ws_out3, N_NODES, DOUT_DIM, DL_DIM);

    // pooling
    pool_kernel<<<N_NODES, dim3(DOUT_DIM), 0, stream>>>(ws_out3, batch, ws_pool, ws_cnt);
    finalize_kernel<<<(N_GRAPH * DOUT_DIM + 255) / 256, blk, 0, stream>>>(ws_pool, ws_cnt, out);
}

// Round 3
// 1300.425 us; speedup vs baseline: 1.0523x; 1.0523x over previous
//
#include <hip/hip_runtime.h>
#include <hip/hip_bf16.h>
#include <stdint.h>
#include <stddef.h>

// Problem constants (from reference)
#define N_NODES  20000
#define N_EDGES  320000
#define N_GRAPH  64
#define F_IN     128
#define E_DIM    32
#define H_DIM    300
#define HID_DIM  600
#define DL_DIM   256
#define DOUT_DIM 128
#define BN_INV_F 0.9999950000374997f
#define EPS_MSG  1e-7f

// ---------------------------------------------------------------------------
// Generic tiled fp32 GEMM: C[M,N] = epilogue(A[M,K] @ B[K,N])
// 64x64 tile, BK=16, 256 threads, 4x4 per thread. Requires K%4==0, N%4==0.
// ---------------------------------------------------------------------------
#define TS 64
#define KS 16

template<bool HAS_BIAS, bool RELU, bool BN>
__global__ __launch_bounds__(256)
void gemm_ep(const float* __restrict__ A, const float* __restrict__ B,
             const float* __restrict__ bias, const float* __restrict__ gamma,
             const float* __restrict__ beta, float* __restrict__ C,
             int M, int N, int K)
{
    __shared__ float As[KS][TS + 4];
    __shared__ float Bs[KS][TS + 4];
    const int tid = threadIdx.x;
    const int bm = blockIdx.y * TS;
    const int bn = blockIdx.x * TS;
    const int tm = (tid / 16) * 4;
    const int tn = (tid % 16) * 4;

    float acc[4][4] = {};

    for (int k0 = 0; k0 < K; k0 += KS) {
        {
            int idx = tid * 4;
            int i = idx / KS;          // tile row 0..63
            int kk = idx % KS;         // 0,4,8,12
            int gm = bm + i, gk = k0 + kk;
            float4 v = make_float4(0.f, 0.f, 0.f, 0.f);
            if (gm < M && gk < K)
                v = *(const float4*)(A + (size_t)gm * K + gk);
            As[kk + 0][i] = v.x; As[kk + 1][i] = v.y;
            As[kk + 2][i] = v.z; As[kk + 3][i] = v.w;
        }
        {
            int idx = tid * 4;
            int kk = idx / TS;         // 0..15
            int j  = idx % TS;         // 0,4,..,60
            int gk = k0 + kk, gn = bn + j;
            float4 v = make_float4(0.f, 0.f, 0.f, 0.f);
            if (gk < K && gn < N)
                v = *(const float4*)(B + (size_t)gk * N + gn);
            *(float4*)&Bs[kk][j] = v;
        }
        __syncthreads();
        #pragma unroll
        for (int kk = 0; kk < KS; ++kk) {
            float4 a = *(const float4*)&As[kk][tm];
            float4 b = *(const float4*)&Bs[kk][tn];
            acc[0][0] += a.x * b.x; acc[0][1] += a.x * b.y;
            acc[0][2] += a.x * b.z; acc[0][3] += a.x * b.w;
            acc[1][0] += a.y * b.x; acc[1][1] += a.y * b.y;
            acc[1][2] += a.y * b.z; acc[1][3] += a.y * b.w;
            acc[2][0] += a.z * b.x; acc[2][1] += a.z * b.y;
            acc[2][2] += a.z * b.z; acc[2][3] += a.z * b.w;
            acc[3][0] += a.w * b.x; acc[3][1] += a.w * b.y;
            acc[3][2] += a.w * b.z; acc[3][3] += a.w * b.w;
        }
        __syncthreads();
    }

    #pragma unroll
    for (int i = 0; i < 4; ++i) {
        int gm = bm + tm + i;
        if (gm >= M) continue;
        #pragma unroll
        for (int j = 0; j < 4; ++j) {
            int gn = bn + tn + j;
            if (gn >= N) continue;
            float v = acc[i][j];
            if (HAS_BIAS) v += bias[gn];
            if (RELU)     v = fmaxf(v, 0.f);
            if (BN)       v = v * (BN_INV_F * gamma[gn]) + beta[gn];
            C[(size_t)gm * N + gn] = v;
        }
    }
}

// ---------------------------------------------------------------------------
// CSR build: histogram of dst, exclusive scan, scatter edge ids, then gather
// edge_attr into destination-sorted order (streaming reads in the hot loop).
// ---------------------------------------------------------------------------
__global__ __launch_bounds__(256)
void hist_kernel(const int* __restrict__ ei, int* __restrict__ counts)
{
    for (int e = blockIdx.x * 256 + threadIdx.x; e < N_EDGES; e += gridDim.x * 256)
        atomicAdd(&counts[ei[N_EDGES + e]], 1);
}

__global__ __launch_bounds__(256)
void scan_kernel(const int* __restrict__ counts, int* __restrict__ rowptr)
{
    __shared__ int sdata[256];
    __shared__ int running;
    int tid = threadIdx.x;
    if (tid == 0) { running = 0; rowptr[0] = 0; }
    __syncthreads();
    for (int base = 0; base < N_NODES; base += 256) {
        int i = base + tid;
        int v = (i < N_NODES) ? counts[i] : 0;
        sdata[tid] = v;
        __syncthreads();
        #pragma unroll
        for (int off = 1; off < 256; off <<= 1) {
            int t = (tid >= off) ? sdata[tid - off] : 0;
            __syncthreads();
            sdata[tid] += t;
            __syncthreads();
        }
        if (i < N_NODES) rowptr[i + 1] = running + sdata[tid];
        __syncthreads();
        if (tid == 255) running += sdata[255];
        __syncthreads();
    }
}

__global__ __launch_bounds__(256)
void scatter_kernel(const int* __restrict__ ei, const int* __restrict__ rowptr,
                    int* __restrict__ cursor, int* __restrict__ perm)
{
    for (int e = blockIdx.x * 256 + threadIdx.x; e < N_EDGES; e += gridDim.x * 256) {
        int d = ei[N_EDGES + e];
        int pos = atomicAdd(&cursor[d], 1);
        perm[rowptr[d] + pos] = e;
    }
}

// gather: ea_sorted[p] = ea[perm[p]]; src_sorted[p] = ei_src[perm[p]]
// one thread per float4 (E*8 threads)
__global__ __launch_bounds__(256)
void gather_kernel(const float* __restrict__ ea, const int* __restrict__ ei,
                   const int* __restrict__ perm, float* __restrict__ ea_sorted,
                   int* __restrict__ src_sorted)
{
    int t = blockIdx.x * 256 + threadIdx.x;
    int p = t >> 3, q = t & 7;
    if (p >= N_EDGES) return;
    int e = perm[p];
    ((float4*)(ea_sorted + (size_t)p * E_DIM))[q] =
        ((const float4*)(ea + (size_t)e * E_DIM))[q];
    if (q == 0) src_sorted[p] = ei[e];
}

// ---------------------------------------------------------------------------
// Aggregation v2: one wave per (node, channel-group).
// No online max (msg bounded ~4.5 -> exp safe in fp32): num/den directly.
// 2x-unrolled independent edge chains; ea reads are sequential (sorted).
// out0 = softmax_agg + xd, written in place over xd.
// ---------------------------------------------------------------------------
__global__ __launch_bounds__(256)
void agg_csr(const float* __restrict__ h, const float* __restrict__ ea_s,
             const int* __restrict__ src_sorted, const int* __restrict__ rowptr,
             const float* __restrict__ We, float* __restrict__ out0)
{
    const int g = blockIdx.y;                      // channel group 0..4
    const int lane = threadIdx.x & 63;
    const int c = g * 64 + lane;
    const bool act = c < H_DIM;
    const int cc = act ? c : (H_DIM - 1);          // clamped for safe loads

    float wreg[E_DIM];
    #pragma unroll
    for (int k = 0; k < E_DIM; ++k)
        wreg[k] = We[(size_t)k * H_DIM + cc];

    const int wglobal = blockIdx.x * 4 + (threadIdx.x >> 6);
    const int nwaves = gridDim.x * 4;

    for (int n = wglobal; n < N_NODES; n += nwaves) {
        const int beg = rowptr[n], end = rowptr[n + 1];
        float den = 0.f, num = 0.f;
        int p = beg;
        for (; p + 1 < end; p += 2) {
            int s0 = src_sorted[p];
            int s1 = src_sorted[p + 1];
            const float4* e0 = (const float4*)(ea_s + (size_t)p * E_DIM);
            const float4* e1 = (const float4*)(ea_s + (size_t)(p + 1) * E_DIM);
            float hv0 = h[(size_t)s0 * H_DIM + cc];
            float hv1 = h[(size_t)s1 * H_DIM + cc];
            float ec0 = 0.f, ec1 = 0.f;
            #pragma unroll
            for (int q = 0; q < 8; ++q) {
                float4 a = e0[q];
                float4 b = e1[q];
                ec0 += a.x * wreg[4 * q] + a.y * wreg[4 * q + 1]
                     + a.z * wreg[4 * q + 2] + a.w * wreg[4 * q + 3];
                ec1 += b.x * wreg[4 * q] + b.y * wreg[4 * q + 1]
                     + b.z * wreg[4 * q + 2] + b.w * wreg[4 * q + 3];
            }
            float msg0 = fmaxf(hv0 + ec0, 0.f) + EPS_MSG;
            float msg1 = fmaxf(hv1 + ec1, 0.f) + EPS_MSG;
            float ex0 = __expf(msg0);
            float ex1 = __expf(msg1);
            den += ex0 + ex1;
            num += msg0 * ex0 + msg1 * ex1;
        }
        if (p < end) {
            int s0 = src_sorted[p];
            const float4* e0 = (const float4*)(ea_s + (size_t)p * E_DIM);
            float hv0 = h[(size_t)s0 * H_DIM + cc];
            float ec0 = 0.f;
            #pragma unroll
            for (int q = 0; q < 8; ++q) {
                float4 a = e0[q];
                ec0 += a.x * wreg[4 * q] + a.y * wreg[4 * q + 1]
                     + a.z * wreg[4 * q + 2] + a.w * wreg[4 * q + 3];
            }
            float msg0 = fmaxf(hv0 + ec0, 0.f) + EPS_MSG;
            float ex0 = __expf(msg0);
            den += ex0;
            num += msg0 * ex0;
        }
        float agg = (end > beg) ? num / den : 0.f;
        if (act) {
            size_t idx = (size_t)n * H_DIM + c;
            out0[idx] = agg + out0[idx];
        }
    }
}

// ---------------------------------------------------------------------------
// pooling
// ---------------------------------------------------------------------------
__global__ __launch_bounds__(128)
void pool_kernel(const float* __restrict__ out3, const int* __restrict__ batch,
                 float* __restrict__ pooled, float* __restrict__ cnt)
{
    int n = blockIdx.x;
    int c = threadIdx.x;
    int g = batch[n];
    atomicAdd(&pooled[(size_t)g * DOUT_DIM + c], out3[(size_t)n * DOUT_DIM + c]);
    if (c == 0) atomicAdd(&cnt[g], 1.f);
}

__global__ __launch_bounds__(256)
void finalize_kernel(const float* __restrict__ pooled, const float* __restrict__ cnt,
                     float* __restrict__ out)
{
    int i = blockIdx.x * 256 + threadIdx.x;
    if (i >= N_GRAPH * DOUT_DIM) return;
    out[i] = pooled[i] / fmaxf(cnt[i / DOUT_DIM], 1.f);
}

// ---------------------------------------------------------------------------
extern "C" void kernel_launch(void* const* d_in, const int* in_sizes, int n_in,
                              void* d_out, int out_size, void* d_ws, size_t ws_size,
                              hipStream_t stream)
{
    const float* x      = (const float*)d_in[0];
    const float* ea     = (const float*)d_in[1];
    const int*   eidx   = (const int*)d_in[2];   // [2,E]: row0=src, row1=dst
    const int*   batch  = (const int*)d_in[3];
    const float* W_src  = (const float*)d_in[4];
    const float* W_edge = (const float*)d_in[5];
    const float* W_dst  = (const float*)d_in[6];
    const float* W1     = (const float*)d_in[7];
    const float* b1     = (const float*)d_in[8];
    const float* g1     = (const float*)d_in[9];
    const float* be1    = (const float*)d_in[10];
    const float* W2     = (const float*)d_in[11];
    const float* b2     = (const float*)d_in[12];
    const float* g2     = (const float*)d_in[13];
    const float* be2    = (const float*)d_in[14];
    const float* W3     = (const float*)d_in[15];
    const float* b3     = (const float*)d_in[16];
    const float* L1     = (const float*)d_in[17];
    const float* bl1    = (const float*)d_in[18];
    const float* L2     = (const float*)d_in[19];
    const float* bl2    = (const float*)d_in[20];
    float* out = (float*)d_out;
    char* ws = (char*)d_ws;

    // Workspace layout (bytes) — peak ~99 MB
    float* ws_h    = (float*)(ws + 0);           // [N,300] 24MB
    float* ws_xd   = (float*)(ws + 24000000);    // [N,300] xd -> out0 (in place)
    float* ws_eas  = (float*)(ws + 48000000);    // [E,32] 41MB (dead after agg)
    float* ws_b1   = (float*)(ws + 48000000);    // [N,600] 48MB (written after agg)
    float* ws_b2   = (float*)(ws + 0);           // [N,600] reuse 0..48M
    float* ws_out1 = (float*)(ws + 48000000);    // [N,300] reuse 48..72M
    float* ws_out2 = (float*)(ws + 72000000);    // [N,256] reuse 72..92.5M
    float* ws_out3 = (float*)(ws + 0);           // [N,128] reuse 0..10.3M
    int*   ws_cnts = (int*)  (ws + 96000000);    // [20000]
    int*   ws_curs = (int*)  (ws + 96100000);    // [20000]
    int*   ws_rptr = (int*)  (ws + 96200000);    // [20001]
    int*   ws_perm = (int*)  (ws + 96300000);    // [320000]
    int*   ws_srcs = (int*)  (ws + 97600000);    // [320000]
    float* ws_pool = (float*)(ws + 98900000);    // [64,128]
    float* ws_cnt  = (float*)(ws + 98940000);    // [64]

    hipMemsetAsync(ws_cnts, 0, N_NODES * sizeof(int), stream);
    hipMemsetAsync(ws_curs, 0, N_NODES * sizeof(int), stream);
    hipMemsetAsync(ws_pool, 0, (size_t)N_GRAPH * DOUT_DIM * 4, stream);
    hipMemsetAsync(ws_cnt,  0, N_GRAPH * 4, stream);

    dim3 blk(256);
    auto grid2 = [](int M, int N) { return dim3((N + TS - 1) / TS, (M + TS - 1) / TS); };

    // h = x @ W_src ; xd = x @ W_dst
    gemm_ep<false, false, false><<<grid2(N_NODES, H_DIM), blk, 0, stream>>>(
        x, W_src, nullptr, nullptr, nullptr, ws_h, N_NODES, H_DIM, F_IN);
    gemm_ep<false, false, false><<<grid2(N_NODES, H_DIM), blk, 0, stream>>>(
        x, W_dst, nullptr, nullptr, nullptr, ws_xd, N_NODES, H_DIM, F_IN);

    // CSR build + edge gather
    hist_kernel<<<512, blk, 0, stream>>>(eidx, ws_cnts);
    scan_kernel<<<1, blk, 0, stream>>>(ws_cnts, ws_rptr);
    scatter_kernel<<<512, blk, 0, stream>>>(eidx, ws_rptr, ws_curs, ws_perm);
    gather_kernel<<<(N_EDGES * 8 + 255) / 256, blk, 0, stream>>>(
        ea, eidx, ws_perm, ws_eas, ws_srcs);

    // softmax aggregation + residual (out0 = agg + xd, in place over xd)
    agg_csr<<<dim3(625, 5), blk, 0, stream>>>(
        ws_h, ws_eas, ws_srcs, ws_rptr, W_edge, ws_xd);

    // MLP chain
    gemm_ep<true, true, true><<<grid2(N_NODES, HID_DIM), blk, 0, stream>>>(
        ws_xd, W1, b1, g1, be1, ws_b1, N_NODES, HID_DIM, H_DIM);
    gemm_ep<true, true, true><<<grid2(N_NODES, HID_DIM), blk, 0, stream>>>(
        ws_b1, W2, b2, g2, be2, ws_b2, N_NODES, HID_DIM, HID_DIM);
    gemm_ep<true, false, false><<<grid2(N_NODES, H_DIM), blk, 0, stream>>>(
        ws_b2, W3, b3, nullptr, nullptr, ws_out1, N_NODES, H_DIM, HID_DIM);
    gemm_ep<true, true, false><<<grid2(N_NODES, DL_DIM), blk, 0, stream>>>(
        ws_out1, L1, bl1, nullptr, nullptr, ws_out2, N_NODES, DL_DIM, H_DIM);
    gemm_ep<true, false, false><<<grid2(N_NODES, DOUT_DIM), blk, 0, stream>>>(
        ws_out2, L2, bl2, nullptr, nullptr, ws_out3, N_NODES, DOUT_DIM, DL_DIM);

    // pooling
    pool_kernel<<<N_NODES, dim3(DOUT_DIM), 0, stream>>>(ws_out3, batch, ws_pool, ws_cnt);
    finalize_kernel<<<(N_GRAPH * DOUT_DIM + 255) / 256, blk, 0, stream>>>(ws_pool, ws_cnt, out);
}

// Round 4
// 871.092 us; speedup vs baseline: 1.5710x; 1.4929x over previous
//
#include <hip/hip_runtime.h>
#include <stdint.h>
#include <stddef.h>

// Problem constants (from reference)
#define N_NODES  20000
#define N_EDGES  320000
#define N_GRAPH  64
#define F_IN     128
#define E_DIM    32
#define H_DIM    300
#define HID_DIM  600
#define DL_DIM   256
#define DOUT_DIM 128
#define BN_INV_F 0.9999950000374997f
#define EPS_MSG  1e-7f

typedef _Float16 f16;
typedef __attribute__((ext_vector_type(8))) _Float16 f16x8;
typedef __attribute__((ext_vector_type(4))) _Float16 f16x4;
typedef __attribute__((ext_vector_type(4))) float f32x4;

// ---------------------------------------------------------------------------
// f16 MFMA GEMM: C[M,Nreal] = epi(A[M,Kpad] @ Bt[Nreal,Kpad]^T)
// A row-major [M,Kpad] f16 (pad cols are zero). Bt is B transposed: [n][k].
// BM=BN=64, BK=32, 256 threads = 4 waves (2x2), each wave 32x32 via 4 MFMA.
// OUT_MODE: 0 = f32 out; 1 = f16 out (+zero cols Nreal..npad); 2 = split
//   (cols<300 -> f32 O1 stride 300; 300..599 -> f16 O2 stride 320, col-300).
// ---------------------------------------------------------------------------
template<bool HAS_BIAS, bool RELU, bool BN, int OUT_MODE>
__global__ __launch_bounds__(256)
void hgemm(const f16* __restrict__ A, const f16* __restrict__ Bt,
           const float* __restrict__ bias, const float* __restrict__ gamma,
           const float* __restrict__ beta,
           void* __restrict__ O1, void* __restrict__ O2,
           int M, int Nreal, int Kpad, int ostride, int npad)
{
    __shared__ __align__(16) f16 As[64][40];
    __shared__ __align__(16) f16 Bs[64][40];
    const int tid  = threadIdx.x;
    const int bm   = blockIdx.y * 64;
    const int bn   = blockIdx.x * 64;
    const int wave = tid >> 6;
    const int lane = tid & 63;
    const int wm   = (wave >> 1) * 32;   // wave M offset
    const int wn   = (wave & 1) * 32;    // wave N offset
    const int fr   = lane & 15;          // A-row / B-col within fragment
    const int kg   = lane >> 4;          // k-group (8 halfs each)
    const int srow = tid >> 2;           // staging row 0..63
    const int skq  = (tid & 3) * 8;      // staging k offset

    const f32x4 z = {0.f, 0.f, 0.f, 0.f};
    f32x4 acc[2][2] = {{z, z}, {z, z}};

    const f16* Arow = A + (size_t)(bm + srow) * Kpad + skq;
    const f16* Brow = Bt + (size_t)(bn + srow) * Kpad + skq;
    const bool avalid = (bm + srow) < M;
    const bool bvalid = (bn + srow) < Nreal;
    const f16x8 zf = {(f16)0, (f16)0, (f16)0, (f16)0,
                      (f16)0, (f16)0, (f16)0, (f16)0};

    for (int k0 = 0; k0 < Kpad; k0 += 32) {
        f16x8 va = zf, vb = zf;
        if (avalid) va = *(const f16x8*)(Arow + k0);
        if (bvalid) vb = *(const f16x8*)(Brow + k0);
        *(f16x8*)&As[srow][skq] = va;
        *(f16x8*)&Bs[srow][skq] = vb;
        __syncthreads();
        f16x8 a0 = *(const f16x8*)&As[wm + fr][kg * 8];
        f16x8 a1 = *(const f16x8*)&As[wm + 16 + fr][kg * 8];
        f16x8 b0 = *(const f16x8*)&Bs[wn + fr][kg * 8];
        f16x8 b1 = *(const f16x8*)&Bs[wn + 16 + fr][kg * 8];
        acc[0][0] = __builtin_amdgcn_mfma_f32_16x16x32_f16(a0, b0, acc[0][0], 0, 0, 0);
        acc[0][1] = __builtin_amdgcn_mfma_f32_16x16x32_f16(a0, b1, acc[0][1], 0, 0, 0);
        acc[1][0] = __builtin_amdgcn_mfma_f32_16x16x32_f16(a1, b0, acc[1][0], 0, 0, 0);
        acc[1][1] = __builtin_amdgcn_mfma_f32_16x16x32_f16(a1, b1, acc[1][1], 0, 0, 0);
        __syncthreads();
    }

    // Epilogue. C layout: col = lane&15 (=fr), row = (lane>>4)*4 + reg (=kg*4+r).
    #pragma unroll
    for (int mi = 0; mi < 2; ++mi) {
        #pragma unroll
        for (int r = 0; r < 4; ++r) {
            int row = bm + wm + mi * 16 + kg * 4 + r;
            if (row >= M) continue;
            #pragma unroll
            for (int ni = 0; ni < 2; ++ni) {
                int col = bn + wn + ni * 16 + fr;
                float v = acc[mi][ni][r];
                if (OUT_MODE == 2) {
                    if (col < 300)
                        ((float*)O1)[(size_t)row * 300 + col] = v;
                    else if (col < 600)
                        ((f16*)O2)[(size_t)row * 320 + (col - 300)] = (f16)v;
                } else {
                    if (col < Nreal) {
                        if (HAS_BIAS) v += bias[col];
                        if (RELU)     v = fmaxf(v, 0.f);
                        if (BN)       v = v * (BN_INV_F * gamma[col]) + beta[col];
                        if (OUT_MODE == 0)
                            ((float*)O1)[(size_t)row * ostride + col] = v;
                        else
                            ((f16*)O1)[(size_t)row * ostride + col] = (f16)v;
                    } else if (OUT_MODE == 1 && col < npad) {
                        ((f16*)O1)[(size_t)row * ostride + col] = (f16)0.f;
                    }
                }
            }
        }
    }
}

// ---------------------------------------------------------------------------
// casts
// ---------------------------------------------------------------------------
__global__ __launch_bounds__(256)
void cast_x(const float* __restrict__ x, f16* __restrict__ xb)
{
    int i = blockIdx.x * 256 + threadIdx.x;
    if (i >= N_NODES * F_IN / 4) return;
    float4 v = ((const float4*)x)[i];
    f16x4 o = {(f16)v.x, (f16)v.y, (f16)v.z, (f16)v.w};
    ((f16x4*)xb)[i] = o;
}

// Fused transpose+cast of all weights into Wt[n][Kpad] f16 (pad k zeroed).
__global__ __launch_bounds__(256)
void cast_weights(const float* __restrict__ Wsrc, const float* __restrict__ Wdst,
                  const float* __restrict__ W1, const float* __restrict__ W2,
                  const float* __restrict__ W3, const float* __restrict__ L1,
                  const float* __restrict__ L2,
                  f16* __restrict__ Wt_sd, f16* __restrict__ Wt1,
                  f16* __restrict__ Wt2, f16* __restrict__ Wt3,
                  f16* __restrict__ WtL1, f16* __restrict__ WtL2)
{
    int t = blockIdx.x * 256 + threadIdx.x;
    if (t < 600 * 128) {                       // Wt_sd: rows 0..299 Wsrc, 300..599 Wdst
        int n = t / 128, k = t % 128;
        const float* W = (n < 300) ? Wsrc : Wdst;
        int nn = (n < 300) ? n : n - 300;
        Wt_sd[t] = (f16)W[(size_t)k * 300 + nn];
        return;
    }
    t -= 600 * 128;
    if (t < 600 * 320) {                       // Wt1 from W1[300,600], Kpad 320
        int n = t / 320, k = t % 320;
        Wt1[t] = (f16)((k < 300) ? W1[(size_t)k * 600 + n] : 0.f);
        return;
    }
    t -= 600 * 320;
    if (t < 600 * 608) {                       // Wt2 from W2[600,600], Kpad 608
        int n = t / 608, k = t % 608;
        Wt2[t] = (f16)((k < 600) ? W2[(size_t)k * 600 + n] : 0.f);
        return;
    }
    t -= 600 * 608;
    if (t < 300 * 608) {                       // Wt3 from W3[600,300], Kpad 608
        int n = t / 608, k = t % 608;
        Wt3[t] = (f16)((k < 600) ? W3[(size_t)k * 300 + n] : 0.f);
        return;
    }
    t -= 300 * 608;
    if (t < 256 * 320) {                       // WtL1 from L1[300,256], Kpad 320
        int n = t / 320, k = t % 320;
        WtL1[t] = (f16)((k < 300) ? L1[(size_t)k * 256 + n] : 0.f);
        return;
    }
    t -= 256 * 320;
    if (t < 128 * 256) {                       // WtL2 from L2[256,128], Kpad 256
        int n = t / 256, k = t % 256;
        WtL2[t] = (f16)L2[(size_t)k * 128 + n];
    }
}

// ---------------------------------------------------------------------------
// CSR build
// ---------------------------------------------------------------------------
__global__ __launch_bounds__(256)
void hist_kernel(const int* __restrict__ ei, int* __restrict__ counts)
{
    for (int e = blockIdx.x * 256 + threadIdx.x; e < N_EDGES; e += gridDim.x * 256)
        atomicAdd(&counts[ei[N_EDGES + e]], 1);
}

__global__ __launch_bounds__(256)
void scan_kernel(const int* __restrict__ counts, int* __restrict__ rowptr)
{
    __shared__ int sdata[256];
    __shared__ int running;
    int tid = threadIdx.x;
    if (tid == 0) { running = 0; rowptr[0] = 0; }
    __syncthreads();
    for (int base = 0; base < N_NODES; base += 256) {
        int i = base + tid;
        int v = (i < N_NODES) ? counts[i] : 0;
        sdata[tid] = v;
        __syncthreads();
        #pragma unroll
        for (int off = 1; off < 256; off <<= 1) {
            int t = (tid >= off) ? sdata[tid - off] : 0;
            __syncthreads();
            sdata[tid] += t;
            __syncthreads();
        }
        if (i < N_NODES) rowptr[i + 1] = running + sdata[tid];
        __syncthreads();
        if (tid == 255) running += sdata[255];
        __syncthreads();
    }
}

__global__ __launch_bounds__(256)
void scatter_kernel(const int* __restrict__ ei, const int* __restrict__ rowptr,
                    int* __restrict__ cursor, int* __restrict__ perm)
{
    for (int e = blockIdx.x * 256 + threadIdx.x; e < N_EDGES; e += gridDim.x * 256) {
        int d = ei[N_EDGES + e];
        int pos = atomicAdd(&cursor[d], 1);
        perm[rowptr[d] + pos] = e;
    }
}

__global__ __launch_bounds__(256)
void gather_kernel(const float* __restrict__ ea, const int* __restrict__ ei,
                   const int* __restrict__ perm, float* __restrict__ ea_sorted,
                   int* __restrict__ src_sorted)
{
    int t = blockIdx.x * 256 + threadIdx.x;
    int p = t >> 3, q = t & 7;
    if (p >= N_EDGES) return;
    int e = perm[p];
    ((float4*)(ea_sorted + (size_t)p * E_DIM))[q] =
        ((const float4*)(ea + (size_t)e * E_DIM))[q];
    if (q == 0) src_sorted[p] = ei[e];
}

// ---------------------------------------------------------------------------
// Aggregation: one wave per (node, channel-group). num/den without max
// (msg bounded -> exp safe in fp32). out0b f16 RMW: out0 = agg + xd.
// ---------------------------------------------------------------------------
__global__ __launch_bounds__(256)
void agg_csr(const float* __restrict__ h, const float* __restrict__ ea_s,
             const int* __restrict__ src_sorted, const int* __restrict__ rowptr,
             const float* __restrict__ We, f16* __restrict__ out0b)
{
    const int g = blockIdx.y;                      // channel group 0..4
    const int lane = threadIdx.x & 63;
    const int c = g * 64 + lane;
    const bool act = c < H_DIM;
    const int cc = act ? c : (H_DIM - 1);          // clamped for safe loads

    float wreg[E_DIM];
    #pragma unroll
    for (int k = 0; k < E_DIM; ++k)
        wreg[k] = We[(size_t)k * H_DIM + cc];

    const int wglobal = blockIdx.x * 4 + (threadIdx.x >> 6);
    const int nwaves = gridDim.x * 4;

    for (int n = wglobal; n < N_NODES; n += nwaves) {
        const int beg = rowptr[n], end = rowptr[n + 1];
        float den = 0.f, num = 0.f;
        int p = beg;
        for (; p + 1 < end; p += 2) {
            int s0 = src_sorted[p];
            int s1 = src_sorted[p + 1];
            const float4* e0 = (const float4*)(ea_s + (size_t)p * E_DIM);
            const float4* e1 = (const float4*)(ea_s + (size_t)(p + 1) * E_DIM);
            float hv0 = h[(size_t)s0 * H_DIM + cc];
            float hv1 = h[(size_t)s1 * H_DIM + cc];
            float ec0 = 0.f, ec1 = 0.f;
            #pragma unroll
            for (int q = 0; q < 8; ++q) {
                float4 a = e0[q];
                float4 b = e1[q];
                ec0 += a.x * wreg[4 * q] + a.y * wreg[4 * q + 1]
                     + a.z * wreg[4 * q + 2] + a.w * wreg[4 * q + 3];
                ec1 += b.x * wreg[4 * q] + b.y * wreg[4 * q + 1]
                     + b.z * wreg[4 * q + 2] + b.w * wreg[4 * q + 3];
            }
            float msg0 = fmaxf(hv0 + ec0, 0.f) + EPS_MSG;
            float msg1 = fmaxf(hv1 + ec1, 0.f) + EPS_MSG;
            float ex0 = __expf(msg0);
            float ex1 = __expf(msg1);
            den += ex0 + ex1;
            num += msg0 * ex0 + msg1 * ex1;
        }
        if (p < end) {
            int s0 = src_sorted[p];
            const float4* e0 = (const float4*)(ea_s + (size_t)p * E_DIM);
            float hv0 = h[(size_t)s0 * H_DIM + cc];
            float ec0 = 0.f;
            #pragma unroll
            for (int q = 0; q < 8; ++q) {
                float4 a = e0[q];
                ec0 += a.x * wreg[4 * q] + a.y * wreg[4 * q + 1]
                     + a.z * wreg[4 * q + 2] + a.w * wreg[4 * q + 3];
            }
            float msg0 = fmaxf(hv0 + ec0, 0.f) + EPS_MSG;
            float ex0 = __expf(msg0);
            den += ex0;
            num += msg0 * ex0;
        }
        float agg = (end > beg) ? num / den : 0.f;
        if (act) {
            size_t idx = (size_t)n * 320 + c;
            out0b[idx] = (f16)(agg + (float)out0b[idx]);   // += xd (stored f16)
        } else if (c < 320) {
            out0b[(size_t)n * 320 + c] = (f16)0.f;          // zero K-pad
        }
    }
}

// ---------------------------------------------------------------------------
// pooling
// ---------------------------------------------------------------------------
__global__ __launch_bounds__(128)
void pool_kernel(const float* __restrict__ out3, const int* __restrict__ batch,
                 float* __restrict__ pooled, float* __restrict__ cnt)
{
    int n = blockIdx.x;
    int c = threadIdx.x;
    int g = batch[n];
    atomicAdd(&pooled[(size_t)g * DOUT_DIM + c], out3[(size_t)n * DOUT_DIM + c]);
    if (c == 0) atomicAdd(&cnt[g], 1.f);
}

__global__ __launch_bounds__(256)
void finalize_kernel(const float* __restrict__ pooled, const float* __restrict__ cnt,
                     float* __restrict__ out)
{
    int i = blockIdx.x * 256 + threadIdx.x;
    if (i >= N_GRAPH * DOUT_DIM) return;
    out[i] = pooled[i] / fmaxf(cnt[i / DOUT_DIM], 1.f);
}

// ---------------------------------------------------------------------------
extern "C" void kernel_launch(void* const* d_in, const int* in_sizes, int n_in,
                              void* d_out, int out_size, void* d_ws, size_t ws_size,
                              hipStream_t stream)
{
    const float* x      = (const float*)d_in[0];
    const float* ea     = (const float*)d_in[1];
    const int*   eidx   = (const int*)d_in[2];   // [2,E]: row0=src, row1=dst
    const int*   batch  = (const int*)d_in[3];
    const float* W_src  = (const float*)d_in[4];
    const float* W_edge = (const float*)d_in[5];
    const float* W_dst  = (const float*)d_in[6];
    const float* W1     = (const float*)d_in[7];
    const float* b1     = (const float*)d_in[8];
    const float* g1     = (const float*)d_in[9];
    const float* be1    = (const float*)d_in[10];
    const float* W2     = (const float*)d_in[11];
    const float* b2     = (const float*)d_in[12];
    const float* g2     = (const float*)d_in[13];
    const float* be2    = (const float*)d_in[14];
    const float* W3     = (const float*)d_in[15];
    const float* b3     = (const float*)d_in[16];
    const float* L1     = (const float*)d_in[17];
    const float* bl1    = (const float*)d_in[18];
    const float* L2     = (const float*)d_in[19];
    const float* bl2    = (const float*)d_in[20];
    float* out = (float*)d_out;
    char* ws = (char*)d_ws;

    // Workspace overlay (peak ~87.9 MB; 98.94 MB known-good)
    float* ws_h     = (float*)(ws + 0);           // [N,300] f32, live gemm_sd->agg
    f16*   ws_b2b   = (f16*)  (ws + 0);           // [N,608] f16, gemm2->gemm3
    float* ws_out3  = (float*)(ws + 0);           // [N,128] f32, gemm5->pool
    float* ws_eas   = (float*)(ws + 24320000);    // [E,32] f32, gather->agg
    f16*   ws_b1b   = (f16*)  (ws + 24320000);    // [N,608] f16, gemm1->gemm2
    f16*   ws_out1b = (f16*)  (ws + 24320000);    // [N,320] f16, gemm3->gemm4
    f16*   ws_out2b = (f16*)  (ws + 37120000);    // [N,256] f16, gemm4->gemm5
    f16*   ws_out0b = (f16*)  (ws + 65280000);    // [N,320] f16, gemm_sd->gemm1
    f16*   ws_xb    = (f16*)  (ws + 78080000);    // [N,128] f16
    f16*   ws_wtsd  = (f16*)  (ws + 83200000);    // [600,128]
    f16*   ws_wt1   = (f16*)  (ws + 83353600);    // [600,320]
    f16*   ws_wt2   = (f16*)  (ws + 83737600);    // [600,608]
    f16*   ws_wt3   = (f16*)  (ws + 84467200);    // [300,608]
    f16*   ws_wtl1  = (f16*)  (ws + 84832000);    // [256,320]
    f16*   ws_wtl2  = (f16*)  (ws + 84995840);    // [128,256]
    int*   ws_cnts  = (int*)  (ws + 85061376);    // [20000]
    int*   ws_curs  = (int*)  (ws + 85141376);    // [20000]
    int*   ws_rptr  = (int*)  (ws + 85221376);    // [20001]
    int*   ws_perm  = (int*)  (ws + 85301392);    // [320000]
    int*   ws_srcs  = (int*)  (ws + 86581392);    // [320000]
    float* ws_pool  = (float*)(ws + 87861392);    // [64,128]
    float* ws_cnt   = (float*)(ws + 87894160);    // [64]

    hipMemsetAsync(ws_cnts, 0, N_NODES * sizeof(int), stream);
    hipMemsetAsync(ws_curs, 0, N_NODES * sizeof(int), stream);
    hipMemsetAsync(ws_pool, 0, (size_t)N_GRAPH * DOUT_DIM * 4 + N_GRAPH * 4, stream);

    dim3 blk(256);

    // casts
    cast_x<<<(N_NODES * F_IN / 4 + 255) / 256, blk, 0, stream>>>(x, ws_xb);
    {
        int total = 600*128 + 600*320 + 600*608 + 300*608 + 256*320 + 128*256;
        cast_weights<<<(total + 255) / 256, blk, 0, stream>>>(
            W_src, W_dst, W1, W2, W3, L1, L2,
            ws_wtsd, ws_wt1, ws_wt2, ws_wt3, ws_wtl1, ws_wtl2);
    }

    // h | xd  = x @ [W_src ; W_dst]  (split epilogue: h f32, xd -> out0b f16)
    hgemm<false, false, false, 2><<<dim3(10, 313), blk, 0, stream>>>(
        ws_xb, ws_wtsd, nullptr, nullptr, nullptr, ws_h, ws_out0b,
        N_NODES, 600, 128, 300, 608);

    // CSR build + edge gather
    hist_kernel<<<512, blk, 0, stream>>>(eidx, ws_cnts);
    scan_kernel<<<1, blk, 0, stream>>>(ws_cnts, ws_rptr);
    scatter_kernel<<<512, blk, 0, stream>>>(eidx, ws_rptr, ws_curs, ws_perm);
    gather_kernel<<<(N_EDGES * 8 + 255) / 256, blk, 0, stream>>>(
        ea, eidx, ws_perm, ws_eas, ws_srcs);

    // softmax aggregation + residual (out0b = agg + xd, f16 RMW)
    agg_csr<<<dim3(625, 5), blk, 0, stream>>>(
        ws_h, ws_eas, ws_srcs, ws_rptr, W_edge, ws_out0b);

    // MLP + encoder chain (f16 MFMA, fp32 accum)
    hgemm<true, true, true, 1><<<dim3(10, 313), blk, 0, stream>>>(
        ws_out0b, ws_wt1, b1, g1, be1, ws_b1b, nullptr,
        N_NODES, 600, 320, 608, 608);
    hgemm<true, true, true, 1><<<dim3(10, 313), blk, 0, stream>>>(
        ws_b1b, ws_wt2, b2, g2, be2, ws_b2b, nullptr,
        N_NODES, 600, 608, 608, 608);
    hgemm<true, false, false, 1><<<dim3(5, 313), blk, 0, stream>>>(
        ws_b2b, ws_wt3, b3, nullptr, nullptr, ws_out1b, nullptr,
        N_NODES, 300, 608, 320, 320);
    hgemm<true, true, false, 1><<<dim3(4, 313), blk, 0, stream>>>(
        ws_out1b, ws_wtl1, bl1, nullptr, nullptr, ws_out2b, nullptr,
        N_NODES, 256, 320, 256, 256);
    hgemm<true, false, false, 0><<<dim3(2, 313), blk, 0, stream>>>(
        ws_out2b, ws_wtl2, bl2, nullptr, nullptr, ws_out3, nullptr,
        N_NODES, 128, 256, 128, 128);

    // pooling
    pool_kernel<<<N_NODES, dim3(DOUT_DIM), 0, stream>>>(ws_out3, batch, ws_pool, ws_cnt);
    finalize_kernel<<<(N_GRAPH * DOUT_DIM + 255) / 256, blk, 0, stream>>>(ws_pool, ws_cnt, out);
}

// Round 5
// 478.169 us; speedup vs baseline: 2.8619x; 1.8217x over previous
//
#include <hip/hip_runtime.h>
#include <stdint.h>
#include <stddef.h>

// Problem constants (from reference)
#define N_NODES  20000
#define N_EDGES  320000
#define N_GRAPH  64
#define F_IN     128
#define E_DIM    32
#define H_DIM    300
#define HID_DIM  600
#define DL_DIM   256
#define DOUT_DIM 128
#define BN_INV_F 0.9999950000374997f
#define EPS_MSG  1e-7f

typedef _Float16 f16;
typedef __attribute__((ext_vector_type(8))) _Float16 f16x8;
typedef __attribute__((ext_vector_type(4))) _Float16 f16x4;
typedef __attribute__((ext_vector_type(4))) float f32x4;

// ---------------------------------------------------------------------------
// f16 MFMA GEMM (validated round 4): C[M,Nreal] = epi(A[M,Kpad] @ Bt[Nreal,Kpad]^T)
// ---------------------------------------------------------------------------
template<bool HAS_BIAS, bool RELU, bool BN, int OUT_MODE>
__global__ __launch_bounds__(256)
void hgemm(const f16* __restrict__ A, const f16* __restrict__ Bt,
           const float* __restrict__ bias, const float* __restrict__ gamma,
           const float* __restrict__ beta,
           void* __restrict__ O1, void* __restrict__ O2,
           int M, int Nreal, int Kpad, int ostride, int npad)
{
    __shared__ __align__(16) f16 As[64][40];
    __shared__ __align__(16) f16 Bs[64][40];
    const int tid  = threadIdx.x;
    const int bm   = blockIdx.y * 64;
    const int bn   = blockIdx.x * 64;
    const int wave = tid >> 6;
    const int lane = tid & 63;
    const int wm   = (wave >> 1) * 32;
    const int wn   = (wave & 1) * 32;
    const int fr   = lane & 15;
    const int kg   = lane >> 4;
    const int srow = tid >> 2;
    const int skq  = (tid & 3) * 8;

    const f32x4 z = {0.f, 0.f, 0.f, 0.f};
    f32x4 acc[2][2] = {{z, z}, {z, z}};

    const f16* Arow = A + (size_t)(bm + srow) * Kpad + skq;
    const f16* Brow = Bt + (size_t)(bn + srow) * Kpad + skq;
    const bool avalid = (bm + srow) < M;
    const bool bvalid = (bn + srow) < Nreal;
    const f16x8 zf = {(f16)0, (f16)0, (f16)0, (f16)0,
                      (f16)0, (f16)0, (f16)0, (f16)0};

    for (int k0 = 0; k0 < Kpad; k0 += 32) {
        f16x8 va = zf, vb = zf;
        if (avalid) va = *(const f16x8*)(Arow + k0);
        if (bvalid) vb = *(const f16x8*)(Brow + k0);
        *(f16x8*)&As[srow][skq] = va;
        *(f16x8*)&Bs[srow][skq] = vb;
        __syncthreads();
        f16x8 a0 = *(const f16x8*)&As[wm + fr][kg * 8];
        f16x8 a1 = *(const f16x8*)&As[wm + 16 + fr][kg * 8];
        f16x8 b0 = *(const f16x8*)&Bs[wn + fr][kg * 8];
        f16x8 b1 = *(const f16x8*)&Bs[wn + 16 + fr][kg * 8];
        acc[0][0] = __builtin_amdgcn_mfma_f32_16x16x32_f16(a0, b0, acc[0][0], 0, 0, 0);
        acc[0][1] = __builtin_amdgcn_mfma_f32_16x16x32_f16(a0, b1, acc[0][1], 0, 0, 0);
        acc[1][0] = __builtin_amdgcn_mfma_f32_16x16x32_f16(a1, b0, acc[1][0], 0, 0, 0);
        acc[1][1] = __builtin_amdgcn_mfma_f32_16x16x32_f16(a1, b1, acc[1][1], 0, 0, 0);
        __syncthreads();
    }

    #pragma unroll
    for (int mi = 0; mi < 2; ++mi) {
        #pragma unroll
        for (int r = 0; r < 4; ++r) {
            int row = bm + wm + mi * 16 + kg * 4 + r;
            if (row >= M) continue;
            #pragma unroll
            for (int ni = 0; ni < 2; ++ni) {
                int col = bn + wn + ni * 16 + fr;
                float v = acc[mi][ni][r];
                if (OUT_MODE == 2) {
                    if (col < 300)
                        ((float*)O1)[(size_t)row * 300 + col] = v;
                    else if (col < 600)
                        ((f16*)O2)[(size_t)row * 320 + (col - 300)] = (f16)v;
                } else {
                    if (col < Nreal) {
                        if (HAS_BIAS) v += bias[col];
                        if (RELU)     v = fmaxf(v, 0.f);
                        if (BN)       v = v * (BN_INV_F * gamma[col]) + beta[col];
                        if (OUT_MODE == 0)
                            ((float*)O1)[(size_t)row * ostride + col] = v;
                        else
                            ((f16*)O1)[(size_t)row * ostride + col] = (f16)v;
                    } else if (OUT_MODE == 1 && col < npad) {
                        ((f16*)O1)[(size_t)row * ostride + col] = (f16)0.f;
                    }
                }
            }
        }
    }
}

// ---------------------------------------------------------------------------
// casts
// ---------------------------------------------------------------------------
__global__ __launch_bounds__(256)
void cast_x(const float* __restrict__ x, f16* __restrict__ xb)
{
    int i = blockIdx.x * 256 + threadIdx.x;
    if (i >= N_NODES * F_IN / 4) return;
    float4 v = ((const float4*)x)[i];
    f16x4 o = {(f16)v.x, (f16)v.y, (f16)v.z, (f16)v.w};
    ((f16x4*)xb)[i] = o;
}

// Fused transpose+cast of all weights into Wt[n][Kpad] f16 (pad k zeroed).
__global__ __launch_bounds__(256)
void cast_weights(const float* __restrict__ Wsrc, const float* __restrict__ Wdst,
                  const float* __restrict__ W1, const float* __restrict__ W2,
                  const float* __restrict__ W3, const float* __restrict__ L1,
                  const float* __restrict__ L2, const float* __restrict__ We,
                  f16* __restrict__ Wt_sd, f16* __restrict__ Wt1,
                  f16* __restrict__ Wt2, f16* __restrict__ Wt3,
                  f16* __restrict__ WtL1, f16* __restrict__ WtL2,
                  f16* __restrict__ Wet)
{
    int t = blockIdx.x * 256 + threadIdx.x;
    if (t < 600 * 128) {
        int n = t / 128, k = t % 128;
        const float* W = (n < 300) ? Wsrc : Wdst;
        int nn = (n < 300) ? n : n - 300;
        Wt_sd[t] = (f16)W[(size_t)k * 300 + nn];
        return;
    }
    t -= 600 * 128;
    if (t < 600 * 320) {
        int n = t / 320, k = t % 320;
        Wt1[t] = (f16)((k < 300) ? W1[(size_t)k * 600 + n] : 0.f);
        return;
    }
    t -= 600 * 320;
    if (t < 600 * 608) {
        int n = t / 608, k = t % 608;
        Wt2[t] = (f16)((k < 600) ? W2[(size_t)k * 600 + n] : 0.f);
        return;
    }
    t -= 600 * 608;
    if (t < 300 * 608) {
        int n = t / 608, k = t % 608;
        Wt3[t] = (f16)((k < 600) ? W3[(size_t)k * 300 + n] : 0.f);
        return;
    }
    t -= 300 * 608;
    if (t < 256 * 320) {
        int n = t / 320, k = t % 320;
        WtL1[t] = (f16)((k < 300) ? L1[(size_t)k * 256 + n] : 0.f);
        return;
    }
    t -= 256 * 320;
    if (t < 128 * 256) {
        int n = t / 256, k = t % 256;
        WtL2[t] = (f16)L2[(size_t)k * 128 + n];
        return;
    }
    t -= 128 * 256;
    if (t < 304 * 32) {                       // Wet[n][k] = We[k][n], rows 300..303 zero
        int n = t / 32, k = t % 32;
        Wet[t] = (f16)((n < 300) ? We[(size_t)k * 300 + n] : 0.f);
    }
}

// ---------------------------------------------------------------------------
// CSR build: histogram, hierarchical scan (3 kernels), scatter, gather(f16)
// ---------------------------------------------------------------------------
__global__ __launch_bounds__(256)
void hist_kernel(const int* __restrict__ ei, int* __restrict__ counts)
{
    for (int e = blockIdx.x * 256 + threadIdx.x; e < N_EDGES; e += gridDim.x * 256)
        atomicAdd(&counts[ei[N_EDGES + e]], 1);
}

__global__ __launch_bounds__(256)
void scan1_kernel(const int* __restrict__ counts, int* __restrict__ rowptr,
                  int* __restrict__ bsum)
{
    __shared__ int sd[256];
    int tid = threadIdx.x;
    int i = blockIdx.x * 256 + tid;
    int v = (i < N_NODES) ? counts[i] : 0;
    sd[tid] = v;
    __syncthreads();
    #pragma unroll
    for (int off = 1; off < 256; off <<= 1) {
        int t = (tid >= off) ? sd[tid - off] : 0;
        __syncthreads();
        sd[tid] += t;
        __syncthreads();
    }
    if (i < N_NODES) rowptr[i + 1] = sd[tid];   // block-local inclusive
    if (tid == 255) bsum[blockIdx.x] = sd[255];
}

__global__ __launch_bounds__(128)
void scan2_kernel(const int* __restrict__ bsum, int* __restrict__ boffs, int nb)
{
    __shared__ int sd[128];
    int tid = threadIdx.x;
    int v = (tid < nb) ? bsum[tid] : 0;
    sd[tid] = v;
    __syncthreads();
    #pragma unroll
    for (int off = 1; off < 128; off <<= 1) {
        int t = (tid >= off) ? sd[tid - off] : 0;
        __syncthreads();
        sd[tid] += t;
        __syncthreads();
    }
    if (tid < nb) boffs[tid] = sd[tid] - v;     // exclusive
}

__global__ __launch_bounds__(256)
void scan3_kernel(int* __restrict__ rowptr, const int* __restrict__ boffs)
{
    int i = blockIdx.x * 256 + threadIdx.x;
    if (i < N_NODES) rowptr[i + 1] += boffs[blockIdx.x];
    if (i == 0) rowptr[0] = 0;
}

__global__ __launch_bounds__(256)
void scatter_kernel(const int* __restrict__ ei, const int* __restrict__ rowptr,
                    int* __restrict__ cursor, int* __restrict__ perm)
{
    for (int e = blockIdx.x * 256 + threadIdx.x; e < N_EDGES; e += gridDim.x * 256) {
        int d = ei[N_EDGES + e];
        int pos = atomicAdd(&cursor[d], 1);
        perm[rowptr[d] + pos] = e;
    }
}

// eaf[p] = (f16)ea[perm[p]]; srcs[p] = ei_src[perm[p]]
__global__ __launch_bounds__(256)
void gather_kernel(const float* __restrict__ ea, const int* __restrict__ ei,
                   const int* __restrict__ perm, f16* __restrict__ eaf,
                   int* __restrict__ srcs)
{
    int t = blockIdx.x * 256 + threadIdx.x;
    int p = t >> 3, q = t & 7;
    if (p >= N_EDGES) return;
    int e = perm[p];
    float4 v = ((const float4*)(ea + (size_t)e * E_DIM))[q];
    f16x4 o = {(f16)v.x, (f16)v.y, (f16)v.z, (f16)v.w};
    ((f16x4*)(eaf + (size_t)p * E_DIM))[q] = o;
    if (q == 0) srcs[p] = ei[e];
}

// ---------------------------------------------------------------------------
// Fused aggregation: block = 320 threads (5 waves) owns NPB=20 nodes.
// Per 64-edge chunk: stage eaf rows -> LDS, MFMA-project through Wet into
// LDS e_buf[64][304] f16, then thread-per-channel walk with 16-deep h
// prefetch accumulating num/den; flush at node boundaries (RMW += xd into
// out0b f16, zero pad cols).
// ---------------------------------------------------------------------------
#define NPB 20

__global__ __launch_bounds__(320)
void agg_mfma(const float* __restrict__ h, const f16* __restrict__ eaf,
              const int* __restrict__ srcs, const int* __restrict__ rptr,
              const f16* __restrict__ Wet, f16* __restrict__ out0b)
{
    __shared__ __align__(16) f16 As[64][40];
    __shared__ __align__(16) f16 e_lds[64 * 304];

    const int tid  = threadIdx.x;
    const int w    = tid >> 6;           // wave 0..4
    const int lane = tid & 63;
    const int fr   = lane & 15;
    const int kg   = lane >> 4;
    const int c    = tid;                // channel owned in accumulate phase
    const bool act = c < H_DIM;

    const int n0 = blockIdx.x * NPB;
    const int n1 = n0 + NPB;
    const int P0 = rptr[n0];
    const int P1 = rptr[n1];

    // B-fragments: wave w owns N-tiles {w, w+5, w+10, w+15} (tile<19)
    f16x8 bf0, bf1, bf2, bf3;
    {
        int t0 = w;
        bf0 = *(const f16x8*)(Wet + (size_t)(t0 * 16 + fr) * 32 + kg * 8);
        bf1 = *(const f16x8*)(Wet + (size_t)((t0 + 5) * 16 + fr) * 32 + kg * 8);
        bf2 = *(const f16x8*)(Wet + (size_t)((t0 + 10) * 16 + fr) * 32 + kg * 8);
        if (t0 + 15 < 19)
            bf3 = *(const f16x8*)(Wet + (size_t)((t0 + 15) * 16 + fr) * 32 + kg * 8);
    }

    const f32x4 z4 = {0.f, 0.f, 0.f, 0.f};

    int n_cur = n0;
    int e_end = (n_cur < n1) ? rptr[n_cur + 1] : 0x7fffffff;
    float num = 0.f, den = 0.f;

    auto flush = [&]() {
        float agg = den > 0.f ? num / den : 0.f;
        size_t idx = (size_t)n_cur * 320 + c;
        if (act)
            out0b[idx] = (f16)(agg + (float)out0b[idx]);
        else
            out0b[idx] = (f16)0.f;           // zero K-pad cols 300..319
        num = 0.f; den = 0.f;
        ++n_cur;
        e_end = (n_cur < n1) ? rptr[n_cur + 1] : 0x7fffffff;
    };

    for (int ck = P0; ck < P1; ck += 64) {
        const int cend = min(ck + 64, P1);
        // ---- stage eaf rows [ck, ck+64) into As (threads 0..255) ----
        if (tid < 256) {
            int row = tid >> 2;
            int kq  = (tid & 3) * 8;
            int p   = ck + row;
            if (p >= N_EDGES) p = N_EDGES - 1;   // clamp (garbage rows unused)
            *(f16x8*)&As[row][kq] = *(const f16x8*)(eaf + (size_t)p * E_DIM + kq);
        }
        __syncthreads();
        // ---- MFMA projection: e_lds[edge][chan] = (As @ Wet^T) ----
        {
            f16x8 af0 = *(const f16x8*)&As[fr][kg * 8];
            f16x8 af1 = *(const f16x8*)&As[16 + fr][kg * 8];
            f16x8 af2 = *(const f16x8*)&As[32 + fr][kg * 8];
            f16x8 af3 = *(const f16x8*)&As[48 + fr][kg * 8];
            #pragma unroll
            for (int i = 0; i < 4; ++i) {
                int t = w + 5 * i;
                if (t >= 19) continue;
                f16x8 bf = (i == 0) ? bf0 : (i == 1) ? bf1 : (i == 2) ? bf2 : bf3;
                #pragma unroll
                for (int mi = 0; mi < 4; ++mi) {
                    f16x8 af = (mi == 0) ? af0 : (mi == 1) ? af1 : (mi == 2) ? af2 : af3;
                    f32x4 d = __builtin_amdgcn_mfma_f32_16x16x32_f16(af, bf, z4, 0, 0, 0);
                    int col = t * 16 + fr;
                    int rbase = mi * 16 + kg * 4;
                    #pragma unroll
                    for (int r = 0; r < 4; ++r)
                        e_lds[(size_t)(rbase + r) * 304 + col] = (f16)d[r];
                }
            }
        }
        __syncthreads();
        // ---- accumulate walk over chunk edges, 16-deep h prefetch ----
        for (int ck2 = ck; ck2 < cend; ck2 += 16) {
            float hv0,hv1,hv2,hv3,hv4,hv5,hv6,hv7,hv8,hv9,hv10,hv11,hv12,hv13,hv14,hv15;
            float ev0,ev1,ev2,ev3,ev4,ev5,ev6,ev7,ev8,ev9,ev10,ev11,ev12,ev13,ev14,ev15;
            #define LOADJ(J, HV, EV)                                              \
                if (ck2 + (J) < cend) {                                           \
                    int s = srcs[ck2 + (J)];                                      \
                    if (act) {                                                    \
                        HV = h[(size_t)s * H_DIM + c];                            \
                        EV = (float)e_lds[(size_t)(ck2 - ck + (J)) * 304 + c];    \
                    }                                                             \
                }
            LOADJ(0,hv0,ev0)   LOADJ(1,hv1,ev1)   LOADJ(2,hv2,ev2)   LOADJ(3,hv3,ev3)
            LOADJ(4,hv4,ev4)   LOADJ(5,hv5,ev5)   LOADJ(6,hv6,ev6)   LOADJ(7,hv7,ev7)
            LOADJ(8,hv8,ev8)   LOADJ(9,hv9,ev9)   LOADJ(10,hv10,ev10) LOADJ(11,hv11,ev11)
            LOADJ(12,hv12,ev12) LOADJ(13,hv13,ev13) LOADJ(14,hv14,ev14) LOADJ(15,hv15,ev15)
            #undef LOADJ
            #define ACCJ(J, HV, EV)                                               \
                if (ck2 + (J) < cend) {                                           \
                    int p = ck2 + (J);                                            \
                    while (p == e_end) flush();                                   \
                    if (act) {                                                    \
                        float msg = fmaxf(HV + EV, 0.f) + EPS_MSG;                \
                        float ex = __expf(msg);                                   \
                        den += ex;                                                \
                        num += msg * ex;                                          \
                    }                                                             \
                }
            ACCJ(0,hv0,ev0)   ACCJ(1,hv1,ev1)   ACCJ(2,hv2,ev2)   ACCJ(3,hv3,ev3)
            ACCJ(4,hv4,ev4)   ACCJ(5,hv5,ev5)   ACCJ(6,hv6,ev6)   ACCJ(7,hv7,ev7)
            ACCJ(8,hv8,ev8)   ACCJ(9,hv9,ev9)   ACCJ(10,hv10,ev10) ACCJ(11,hv11,ev11)
            ACCJ(12,hv12,ev12) ACCJ(13,hv13,ev13) ACCJ(14,hv14,ev14) ACCJ(15,hv15,ev15)
            #undef ACCJ
        }
        __syncthreads();   // e_lds/As consumed before next chunk overwrites
    }
    // flush trailing node(s) (incl. empty nodes / zero-edge blocks)
    while (n_cur < n1) flush();
}

// ---------------------------------------------------------------------------
// segmented pooling (batch is sorted)
// ---------------------------------------------------------------------------
#define POOL_NPB 128
__global__ __launch_bounds__(128)
void pool_seg(const float* __restrict__ out3, const int* __restrict__ batch,
              float* __restrict__ pooled, float* __restrict__ cnt)
{
    int c = threadIdx.x;
    int n0 = blockIdx.x * POOL_NPB;
    int n1 = min(n0 + POOL_NPB, N_NODES);
    int g = batch[n0];
    float s = 0.f, cn = 0.f;
    for (int n = n0; n < n1; ++n) {
        int gn = batch[n];
        if (gn != g) {
            atomicAdd(&pooled[(size_t)g * DOUT_DIM + c], s);
            if (c == 0) atomicAdd(&cnt[g], cn);
            g = gn; s = 0.f; cn = 0.f;
        }
        s += out3[(size_t)n * DOUT_DIM + c];
        cn += 1.f;
    }
    atomicAdd(&pooled[(size_t)g * DOUT_DIM + c], s);
    if (c == 0) atomicAdd(&cnt[g], cn);
}

__global__ __launch_bounds__(256)
void finalize_kernel(const float* __restrict__ pooled, const float* __restrict__ cnt,
                     float* __restrict__ out)
{
    int i = blockIdx.x * 256 + threadIdx.x;
    if (i >= N_GRAPH * DOUT_DIM) return;
    out[i] = pooled[i] / fmaxf(cnt[i / DOUT_DIM], 1.f);
}

// ---------------------------------------------------------------------------
extern "C" void kernel_launch(void* const* d_in, const int* in_sizes, int n_in,
                              void* d_out, int out_size, void* d_ws, size_t ws_size,
                              hipStream_t stream)
{
    const float* x      = (const float*)d_in[0];
    const float* ea     = (const float*)d_in[1];
    const int*   eidx   = (const int*)d_in[2];
    const int*   batch  = (const int*)d_in[3];
    const float* W_src  = (const float*)d_in[4];
    const float* W_edge = (const float*)d_in[5];
    const float* W_dst  = (const float*)d_in[6];
    const float* W1     = (const float*)d_in[7];
    const float* b1     = (const float*)d_in[8];
    const float* g1     = (const float*)d_in[9];
    const float* be1    = (const float*)d_in[10];
    const float* W2     = (const float*)d_in[11];
    const float* b2     = (const float*)d_in[12];
    const float* g2     = (const float*)d_in[13];
    const float* be2    = (const float*)d_in[14];
    const float* W3     = (const float*)d_in[15];
    const float* b3     = (const float*)d_in[16];
    const float* L1     = (const float*)d_in[17];
    const float* bl1    = (const float*)d_in[18];
    const float* L2     = (const float*)d_in[19];
    const float* bl2    = (const float*)d_in[20];
    float* out = (float*)d_out;
    char* ws = (char*)d_ws;

    // Workspace overlay (peak ~87.9 MB; 98.94 MB known-good)
    float* ws_h     = (float*)(ws + 0);           // [N,300] f32, gemm_sd->agg
    f16*   ws_b2b   = (f16*)  (ws + 0);           // [N,608] f16, gemm2->gemm3
    float* ws_out3  = (float*)(ws + 0);           // [N,128] f32, gemm5->pool
    f16*   ws_eaf   = (f16*)  (ws + 24320000);    // [E,32] f16, gather->agg
    f16*   ws_b1b   = (f16*)  (ws + 24320000);    // [N,608] f16, gemm1->gemm2
    f16*   ws_out1b = (f16*)  (ws + 24320000);    // [N,320] f16, gemm3->gemm4
    f16*   ws_out2b = (f16*)  (ws + 37120000);    // [N,256] f16, gemm4->gemm5
    f16*   ws_out0b = (f16*)  (ws + 65280000);    // [N,320] f16, gemm_sd->gemm1
    f16*   ws_xb    = (f16*)  (ws + 78080000);    // [N,128] f16
    f16*   ws_wtsd  = (f16*)  (ws + 83200000);
    f16*   ws_wt1   = (f16*)  (ws + 83353600);
    f16*   ws_wt2   = (f16*)  (ws + 83737600);
    f16*   ws_wt3   = (f16*)  (ws + 84467200);
    f16*   ws_wtl1  = (f16*)  (ws + 84832000);
    f16*   ws_wtl2  = (f16*)  (ws + 84995840);
    f16*   ws_wet   = (f16*)  (ws + 85061376);    // [304,32] f16
    int*   ws_cnts  = (int*)  (ws + 85080832);
    int*   ws_curs  = (int*)  (ws + 85160832);
    int*   ws_rptr  = (int*)  (ws + 85240832);    // [20001]
    int*   ws_perm  = (int*)  (ws + 85320848);    // [E]
    int*   ws_srcs  = (int*)  (ws + 86600848);    // [E]
    float* ws_pool  = (float*)(ws + 87880848);    // [64,128]
    float* ws_cnt   = (float*)(ws + 87913616);    // [64]
    int*   ws_bsum  = (int*)  (ws + 87913872);    // [128]
    int*   ws_boffs = (int*)  (ws + 87914384);    // [128]

    hipMemsetAsync(ws_cnts, 0, N_NODES * sizeof(int), stream);
    hipMemsetAsync(ws_curs, 0, N_NODES * sizeof(int), stream);
    hipMemsetAsync(ws_pool, 0, (size_t)N_GRAPH * DOUT_DIM * 4 + N_GRAPH * 4, stream);

    dim3 blk(256);

    // casts
    cast_x<<<(N_NODES * F_IN / 4 + 255) / 256, blk, 0, stream>>>(x, ws_xb);
    {
        int total = 600*128 + 600*320 + 600*608 + 300*608 + 256*320 + 128*256 + 304*32;
        cast_weights<<<(total + 255) / 256, blk, 0, stream>>>(
            W_src, W_dst, W1, W2, W3, L1, L2, W_edge,
            ws_wtsd, ws_wt1, ws_wt2, ws_wt3, ws_wtl1, ws_wtl2, ws_wet);
    }

    // h | xd  = x @ [W_src ; W_dst]
    hgemm<false, false, false, 2><<<dim3(10, 313), blk, 0, stream>>>(
        ws_xb, ws_wtsd, nullptr, nullptr, nullptr, ws_h, ws_out0b,
        N_NODES, 600, 128, 300, 608);

    // CSR build + gather
    hist_kernel<<<512, blk, 0, stream>>>(eidx, ws_cnts);
    {
        int nb = (N_NODES + 255) / 256;   // 79
        scan1_kernel<<<nb, blk, 0, stream>>>(ws_cnts, ws_rptr, ws_bsum);
        scan2_kernel<<<1, dim3(128), 0, stream>>>(ws_bsum, ws_boffs, nb);
        scan3_kernel<<<nb, blk, 0, stream>>>(ws_rptr, ws_boffs);
    }
    scatter_kernel<<<512, blk, 0, stream>>>(eidx, ws_rptr, ws_curs, ws_perm);
    gather_kernel<<<(N_EDGES * 8 + 255) / 256, blk, 0, stream>>>(
        ea, eidx, ws_perm, ws_eaf, ws_srcs);

    // fused MFMA aggregation (out0b = softmax_agg + xd, RMW)
    agg_mfma<<<N_NODES / NPB, dim3(320), 0, stream>>>(
        ws_h, ws_eaf, ws_srcs, ws_rptr, ws_wet, ws_out0b);

    // MLP + encoder chain (f16 MFMA, fp32 accum)
    hgemm<true, true, true, 1><<<dim3(10, 313), blk, 0, stream>>>(
        ws_out0b, ws_wt1, b1, g1, be1, ws_b1b, nullptr,
        N_NODES, 600, 320, 608, 608);
    hgemm<true, true, true, 1><<<dim3(10, 313), blk, 0, stream>>>(
        ws_b1b, ws_wt2, b2, g2, be2, ws_b2b, nullptr,
        N_NODES, 600, 608, 608, 608);
    hgemm<true, false, false, 1><<<dim3(5, 313), blk, 0, stream>>>(
        ws_b2b, ws_wt3, b3, nullptr, nullptr, ws_out1b, nullptr,
        N_NODES, 300, 608, 320, 320);
    hgemm<true, true, false, 1><<<dim3(4, 313), blk, 0, stream>>>(
        ws_out1b, ws_wtl1, bl1, nullptr, nullptr, ws_out2b, nullptr,
        N_NODES, 256, 320, 256, 256);
    hgemm<true, false, false, 0><<<dim3(2, 313), blk, 0, stream>>>(
        ws_out2b, ws_wtl2, bl2, nullptr, nullptr, ws_out3, nullptr,
        N_NODES, 128, 256, 128, 128);

    // pooling
    pool_seg<<<(N_NODES + POOL_NPB - 1) / POOL_NPB, dim3(128), 0, stream>>>(
        ws_out3, batch, ws_pool, ws_cnt);
    finalize_kernel<<<(N_GRAPH * DOUT_DIM + 255) / 256, blk, 0, stream>>>(
        ws_pool, ws_cnt, out);
}

// Round 6
// 468.759 us; speedup vs baseline: 2.9193x; 1.0201x over previous
//
#include <hip/hip_runtime.h>
#include <stdint.h>
#include <stddef.h>

// Problem constants (from reference)
#define N_NODES  20000
#define N_EDGES  320000
#define N_GRAPH  64
#define F_IN     128
#define E_DIM    32
#define H_DIM    300
#define HID_DIM  600
#define DL_DIM   256
#define DOUT_DIM 128
#define BN_INV_F 0.9999950000374997f
#define EPS_MSG  1e-7f

typedef _Float16 f16;
typedef __attribute__((ext_vector_type(8))) _Float16 f16x8;
typedef __attribute__((ext_vector_type(4))) _Float16 f16x4;
typedef __attribute__((ext_vector_type(4))) float f32x4;

// ---------------------------------------------------------------------------
// f16 MFMA GEMM (validated round 4): C[M,Nreal] = epi(A[M,Kpad] @ Bt[Nreal,Kpad]^T)
// OUT_MODE: 0 = f32 out; 1 = f16 out (+zero cols Nreal..npad); 2 = split
//   (cols<300 -> f16 O1 stride 304 [h]; 300..599 -> f16 O2 stride 320, col-300 [xd]).
// ---------------------------------------------------------------------------
template<bool HAS_BIAS, bool RELU, bool BN, int OUT_MODE>
__global__ __launch_bounds__(256)
void hgemm(const f16* __restrict__ A, const f16* __restrict__ Bt,
           const float* __restrict__ bias, const float* __restrict__ gamma,
           const float* __restrict__ beta,
           void* __restrict__ O1, void* __restrict__ O2,
           int M, int Nreal, int Kpad, int ostride, int npad)
{
    __shared__ __align__(16) f16 As[64][40];
    __shared__ __align__(16) f16 Bs[64][40];
    const int tid  = threadIdx.x;
    const int bm   = blockIdx.y * 64;
    const int bn   = blockIdx.x * 64;
    const int wave = tid >> 6;
    const int lane = tid & 63;
    const int wm   = (wave >> 1) * 32;
    const int wn   = (wave & 1) * 32;
    const int fr   = lane & 15;
    const int kg   = lane >> 4;
    const int srow = tid >> 2;
    const int skq  = (tid & 3) * 8;

    const f32x4 z = {0.f, 0.f, 0.f, 0.f};
    f32x4 acc[2][2] = {{z, z}, {z, z}};

    const f16* Arow = A + (size_t)(bm + srow) * Kpad + skq;
    const f16* Brow = Bt + (size_t)(bn + srow) * Kpad + skq;
    const bool avalid = (bm + srow) < M;
    const bool bvalid = (bn + srow) < Nreal;
    const f16x8 zf = {(f16)0, (f16)0, (f16)0, (f16)0,
                      (f16)0, (f16)0, (f16)0, (f16)0};

    for (int k0 = 0; k0 < Kpad; k0 += 32) {
        f16x8 va = zf, vb = zf;
        if (avalid) va = *(const f16x8*)(Arow + k0);
        if (bvalid) vb = *(const f16x8*)(Brow + k0);
        *(f16x8*)&As[srow][skq] = va;
        *(f16x8*)&Bs[srow][skq] = vb;
        __syncthreads();
        f16x8 a0 = *(const f16x8*)&As[wm + fr][kg * 8];
        f16x8 a1 = *(const f16x8*)&As[wm + 16 + fr][kg * 8];
        f16x8 b0 = *(const f16x8*)&Bs[wn + fr][kg * 8];
        f16x8 b1 = *(const f16x8*)&Bs[wn + 16 + fr][kg * 8];
        acc[0][0] = __builtin_amdgcn_mfma_f32_16x16x32_f16(a0, b0, acc[0][0], 0, 0, 0);
        acc[0][1] = __builtin_amdgcn_mfma_f32_16x16x32_f16(a0, b1, acc[0][1], 0, 0, 0);
        acc[1][0] = __builtin_amdgcn_mfma_f32_16x16x32_f16(a1, b0, acc[1][0], 0, 0, 0);
        acc[1][1] = __builtin_amdgcn_mfma_f32_16x16x32_f16(a1, b1, acc[1][1], 0, 0, 0);
        __syncthreads();
    }

    #pragma unroll
    for (int mi = 0; mi < 2; ++mi) {
        #pragma unroll
        for (int r = 0; r < 4; ++r) {
            int row = bm + wm + mi * 16 + kg * 4 + r;
            if (row >= M) continue;
            #pragma unroll
            for (int ni = 0; ni < 2; ++ni) {
                int col = bn + wn + ni * 16 + fr;
                float v = acc[mi][ni][r];
                if (OUT_MODE == 2) {
                    if (col < 300)
                        ((f16*)O1)[(size_t)row * 304 + col] = (f16)v;   // h f16
                    else if (col < 600)
                        ((f16*)O2)[(size_t)row * 320 + (col - 300)] = (f16)v;
                } else {
                    if (col < Nreal) {
                        if (HAS_BIAS) v += bias[col];
                        if (RELU)     v = fmaxf(v, 0.f);
                        if (BN)       v = v * (BN_INV_F * gamma[col]) + beta[col];
                        if (OUT_MODE == 0)
                            ((float*)O1)[(size_t)row * ostride + col] = v;
                        else
                            ((f16*)O1)[(size_t)row * ostride + col] = (f16)v;
                    } else if (OUT_MODE == 1 && col < npad) {
                        ((f16*)O1)[(size_t)row * ostride + col] = (f16)0.f;
                    }
                }
            }
        }
    }
}

// ---------------------------------------------------------------------------
// casts
// ---------------------------------------------------------------------------
__global__ __launch_bounds__(256)
void cast_x(const float* __restrict__ x, f16* __restrict__ xb)
{
    int i = blockIdx.x * 256 + threadIdx.x;
    if (i >= N_NODES * F_IN / 4) return;
    float4 v = ((const float4*)x)[i];
    f16x4 o = {(f16)v.x, (f16)v.y, (f16)v.z, (f16)v.w};
    ((f16x4*)xb)[i] = o;
}

// Fused transpose+cast of all weights into Wt[n][Kpad] f16 (pad k zeroed).
__global__ __launch_bounds__(256)
void cast_weights(const float* __restrict__ Wsrc, const float* __restrict__ Wdst,
                  const float* __restrict__ W1, const float* __restrict__ W2,
                  const float* __restrict__ W3, const float* __restrict__ L1,
                  const float* __restrict__ L2, const float* __restrict__ We,
                  f16* __restrict__ Wt_sd, f16* __restrict__ Wt1,
                  f16* __restrict__ Wt2, f16* __restrict__ Wt3,
                  f16* __restrict__ WtL1, f16* __restrict__ WtL2,
                  f16* __restrict__ Wet)
{
    int t = blockIdx.x * 256 + threadIdx.x;
    if (t < 600 * 128) {
        int n = t / 128, k = t % 128;
        const float* W = (n < 300) ? Wsrc : Wdst;
        int nn = (n < 300) ? n : n - 300;
        Wt_sd[t] = (f16)W[(size_t)k * 300 + nn];
        return;
    }
    t -= 600 * 128;
    if (t < 600 * 320) {
        int n = t / 320, k = t % 320;
        Wt1[t] = (f16)((k < 300) ? W1[(size_t)k * 600 + n] : 0.f);
        return;
    }
    t -= 600 * 320;
    if (t < 600 * 608) {
        int n = t / 608, k = t % 608;
        Wt2[t] = (f16)((k < 600) ? W2[(size_t)k * 600 + n] : 0.f);
        return;
    }
    t -= 600 * 608;
    if (t < 300 * 608) {
        int n = t / 608, k = t % 608;
        Wt3[t] = (f16)((k < 600) ? W3[(size_t)k * 300 + n] : 0.f);
        return;
    }
    t -= 300 * 608;
    if (t < 256 * 320) {
        int n = t / 320, k = t % 320;
        WtL1[t] = (f16)((k < 300) ? L1[(size_t)k * 256 + n] : 0.f);
        return;
    }
    t -= 256 * 320;
    if (t < 128 * 256) {
        int n = t / 256, k = t % 256;
        WtL2[t] = (f16)L2[(size_t)k * 128 + n];
        return;
    }
    t -= 128 * 256;
    if (t < 304 * 32) {                       // Wet[n][k] = We[k][n], rows 300..303 zero
        int n = t / 32, k = t % 32;
        Wet[t] = (f16)((n < 300) ? We[(size_t)k * 300 + n] : 0.f);
    }
}

// ---------------------------------------------------------------------------
// CSR build: histogram, hierarchical scan (3 kernels), scatter, gather(f16)
// ---------------------------------------------------------------------------
__global__ __launch_bounds__(256)
void hist_kernel(const int* __restrict__ ei, int* __restrict__ counts)
{
    for (int e = blockIdx.x * 256 + threadIdx.x; e < N_EDGES; e += gridDim.x * 256)
        atomicAdd(&counts[ei[N_EDGES + e]], 1);
}

__global__ __launch_bounds__(256)
void scan1_kernel(const int* __restrict__ counts, int* __restrict__ rowptr,
                  int* __restrict__ bsum)
{
    __shared__ int sd[256];
    int tid = threadIdx.x;
    int i = blockIdx.x * 256 + tid;
    int v = (i < N_NODES) ? counts[i] : 0;
    sd[tid] = v;
    __syncthreads();
    #pragma unroll
    for (int off = 1; off < 256; off <<= 1) {
        int t = (tid >= off) ? sd[tid - off] : 0;
        __syncthreads();
        sd[tid] += t;
        __syncthreads();
    }
    if (i < N_NODES) rowptr[i + 1] = sd[tid];   // block-local inclusive
    if (tid == 255) bsum[blockIdx.x] = sd[255];
}

__global__ __launch_bounds__(128)
void scan2_kernel(const int* __restrict__ bsum, int* __restrict__ boffs, int nb)
{
    __shared__ int sd[128];
    int tid = threadIdx.x;
    int v = (tid < nb) ? bsum[tid] : 0;
    sd[tid] = v;
    __syncthreads();
    #pragma unroll
    for (int off = 1; off < 128; off <<= 1) {
        int t = (tid >= off) ? sd[tid - off] : 0;
        __syncthreads();
        sd[tid] += t;
        __syncthreads();
    }
    if (tid < nb) boffs[tid] = sd[tid] - v;     // exclusive
}

__global__ __launch_bounds__(256)
void scan3_kernel(int* __restrict__ rowptr, const int* __restrict__ boffs)
{
    int i = blockIdx.x * 256 + threadIdx.x;
    if (i < N_NODES) rowptr[i + 1] += boffs[blockIdx.x];
    if (i == 0) rowptr[0] = 0;
}

__global__ __launch_bounds__(256)
void scatter_kernel(const int* __restrict__ ei, const int* __restrict__ rowptr,
                    int* __restrict__ cursor, int* __restrict__ perm)
{
    for (int e = blockIdx.x * 256 + threadIdx.x; e < N_EDGES; e += gridDim.x * 256) {
        int d = ei[N_EDGES + e];
        int pos = atomicAdd(&cursor[d], 1);
        perm[rowptr[d] + pos] = e;
    }
}

// eaf[p] = (f16)ea[perm[p]]; srcs[p] = ei_src[perm[p]]
__global__ __launch_bounds__(256)
void gather_kernel(const float* __restrict__ ea, const int* __restrict__ ei,
                   const int* __restrict__ perm, f16* __restrict__ eaf,
                   int* __restrict__ srcs)
{
    int t = blockIdx.x * 256 + threadIdx.x;
    int p = t >> 3, q = t & 7;
    if (p >= N_EDGES) return;
    int e = perm[p];
    float4 v = ((const float4*)(ea + (size_t)e * E_DIM))[q];
    f16x4 o = {(f16)v.x, (f16)v.y, (f16)v.z, (f16)v.w};
    ((f16x4*)(eaf + (size_t)p * E_DIM))[q] = o;
    if (q == 0) srcs[p] = ei[e];
}

// ---------------------------------------------------------------------------
// Fused aggregation v2: block = 320 threads (5 waves) owns NPB=10 nodes.
// 32-edge chunks (22.4 KB LDS -> 6 blocks/CU). srcs staged in LDS. e_lds
// stride 308 (kg offset = 8 mod 32 banks -> conflict-free stores). h read
// as f16 (stride 304). Thread = channel; 16-deep h prefetch; flush at node
// boundaries (RMW += xd into out0b f16, zero pad cols).
// ---------------------------------------------------------------------------
#define NPB 10
#define CHK 32
#define ELDS_STRIDE 308

__global__ __launch_bounds__(320)
void agg_mfma(const f16* __restrict__ hf, const f16* __restrict__ eaf,
              const int* __restrict__ srcs, const int* __restrict__ rptr,
              const f16* __restrict__ Wet, f16* __restrict__ out0b)
{
    __shared__ __align__(16) f16 As[CHK][40];
    __shared__ __align__(16) f16 e_lds[CHK * ELDS_STRIDE];
    __shared__ int s_lds[CHK];

    const int tid  = threadIdx.x;
    const int w    = tid >> 6;           // wave 0..4
    const int lane = tid & 63;
    const int fr   = lane & 15;
    const int kg   = lane >> 4;
    const int c    = tid;                // channel owned in accumulate phase
    const bool act = c < H_DIM;

    const int n0 = blockIdx.x * NPB;
    const int n1 = n0 + NPB;
    const int P0 = rptr[n0];
    const int P1 = rptr[n1];

    // B-fragments: wave w owns N-tiles {w, w+5, w+10, w+15} (tile<19)
    f16x8 bf0, bf1, bf2, bf3;
    {
        int t0 = w;
        bf0 = *(const f16x8*)(Wet + (size_t)(t0 * 16 + fr) * 32 + kg * 8);
        bf1 = *(const f16x8*)(Wet + (size_t)((t0 + 5) * 16 + fr) * 32 + kg * 8);
        bf2 = *(const f16x8*)(Wet + (size_t)((t0 + 10) * 16 + fr) * 32 + kg * 8);
        if (t0 + 15 < 19)
            bf3 = *(const f16x8*)(Wet + (size_t)((t0 + 15) * 16 + fr) * 32 + kg * 8);
    }

    const f32x4 z4 = {0.f, 0.f, 0.f, 0.f};

    int n_cur = n0;
    int e_end = (n_cur < n1) ? rptr[n_cur + 1] : 0x7fffffff;
    float num = 0.f, den = 0.f;

    auto flush = [&]() {
        float agg = den > 0.f ? num / den : 0.f;
        size_t idx = (size_t)n_cur * 320 + c;
        if (act)
            out0b[idx] = (f16)(agg + (float)out0b[idx]);
        else
            out0b[idx] = (f16)0.f;           // zero K-pad cols 300..319
        num = 0.f; den = 0.f;
        ++n_cur;
        e_end = (n_cur < n1) ? rptr[n_cur + 1] : 0x7fffffff;
    };

    for (int ck = P0; ck < P1; ck += CHK) {
        const int cend = min(ck + CHK, P1);
        // ---- stage eaf rows + srcs for [ck, ck+32) ----
        if (tid < 128) {
            int row = tid >> 2;
            int kq  = (tid & 3) * 8;
            int p   = ck + row;
            if (p >= N_EDGES) p = N_EDGES - 1;   // clamp (garbage rows unused)
            *(f16x8*)&As[row][kq] = *(const f16x8*)(eaf + (size_t)p * E_DIM + kq);
        } else if (tid < 128 + CHK) {
            int j = tid - 128;
            int p = ck + j;
            s_lds[j] = srcs[p < N_EDGES ? p : N_EDGES - 1];
        }
        __syncthreads();
        // ---- MFMA projection: e_lds[edge][chan] = (As @ Wet^T) ----
        {
            f16x8 af0 = *(const f16x8*)&As[fr][kg * 8];
            f16x8 af1 = *(const f16x8*)&As[16 + fr][kg * 8];
            #pragma unroll
            for (int i = 0; i < 4; ++i) {
                int t = w + 5 * i;
                if (t >= 19) continue;
                f16x8 bf = (i == 0) ? bf0 : (i == 1) ? bf1 : (i == 2) ? bf2 : bf3;
                #pragma unroll
                for (int mi = 0; mi < 2; ++mi) {
                    f16x8 af = (mi == 0) ? af0 : af1;
                    f32x4 d = __builtin_amdgcn_mfma_f32_16x16x32_f16(af, bf, z4, 0, 0, 0);
                    int col = t * 16 + fr;
                    int rbase = mi * 16 + kg * 4;
                    #pragma unroll
                    for (int r = 0; r < 4; ++r)
                        e_lds[(size_t)(rbase + r) * ELDS_STRIDE + col] = (f16)d[r];
                }
            }
        }
        __syncthreads();
        // ---- accumulate walk over chunk edges, 16-deep h prefetch ----
        for (int ck2 = ck; ck2 < cend; ck2 += 16) {
            float hv0,hv1,hv2,hv3,hv4,hv5,hv6,hv7,hv8,hv9,hv10,hv11,hv12,hv13,hv14,hv15;
            float ev0,ev1,ev2,ev3,ev4,ev5,ev6,ev7,ev8,ev9,ev10,ev11,ev12,ev13,ev14,ev15;
            #define LOADJ(J, HV, EV)                                                  \
                if (ck2 + (J) < cend) {                                               \
                    int s = s_lds[ck2 - ck + (J)];                                    \
                    if (act) {                                                        \
                        HV = (float)hf[(size_t)s * 304 + c];                          \
                        EV = (float)e_lds[(size_t)(ck2 - ck + (J)) * ELDS_STRIDE + c];\
                    }                                                                 \
                }
            LOADJ(0,hv0,ev0)   LOADJ(1,hv1,ev1)   LOADJ(2,hv2,ev2)   LOADJ(3,hv3,ev3)
            LOADJ(4,hv4,ev4)   LOADJ(5,hv5,ev5)   LOADJ(6,hv6,ev6)   LOADJ(7,hv7,ev7)
            LOADJ(8,hv8,ev8)   LOADJ(9,hv9,ev9)   LOADJ(10,hv10,ev10) LOADJ(11,hv11,ev11)
            LOADJ(12,hv12,ev12) LOADJ(13,hv13,ev13) LOADJ(14,hv14,ev14) LOADJ(15,hv15,ev15)
            #undef LOADJ
            #define ACCJ(J, HV, EV)                                               \
                if (ck2 + (J) < cend) {                                           \
                    int p = ck2 + (J);                                            \
                    while (p == e_end) flush();                                   \
                    if (act) {                                                    \
                        float msg = fmaxf(HV + EV, 0.f) + EPS_MSG;                \
                        float ex = __expf(msg);                                   \
                        den += ex;                                                \
                        num += msg * ex;                                          \
                    }                                                             \
                }
            ACCJ(0,hv0,ev0)   ACCJ(1,hv1,ev1)   ACCJ(2,hv2,ev2)   ACCJ(3,hv3,ev3)
            ACCJ(4,hv4,ev4)   ACCJ(5,hv5,ev5)   ACCJ(6,hv6,ev6)   ACCJ(7,hv7,ev7)
            ACCJ(8,hv8,ev8)   ACCJ(9,hv9,ev9)   ACCJ(10,hv10,ev10) ACCJ(11,hv11,ev11)
            ACCJ(12,hv12,ev12) ACCJ(13,hv13,ev13) ACCJ(14,hv14,ev14) ACCJ(15,hv15,ev15)
            #undef ACCJ
        }
        __syncthreads();   // e_lds/As/s_lds consumed before next chunk overwrites
    }
    // flush trailing node(s) (incl. empty nodes / zero-edge blocks)
    while (n_cur < n1) flush();
}

// ---------------------------------------------------------------------------
// segmented pooling (batch is sorted)
// ---------------------------------------------------------------------------
#define POOL_NPB 128
__global__ __launch_bounds__(128)
void pool_seg(const float* __restrict__ out3, const int* __restrict__ batch,
              float* __restrict__ pooled, float* __restrict__ cnt)
{
    int c = threadIdx.x;
    int n0 = blockIdx.x * POOL_NPB;
    int n1 = min(n0 + POOL_NPB, N_NODES);
    int g = batch[n0];
    float s = 0.f, cn = 0.f;
    for (int n = n0; n < n1; ++n) {
        int gn = batch[n];
        if (gn != g) {
            atomicAdd(&pooled[(size_t)g * DOUT_DIM + c], s);
            if (c == 0) atomicAdd(&cnt[g], cn);
            g = gn; s = 0.f; cn = 0.f;
        }
        s += out3[(size_t)n * DOUT_DIM + c];
        cn += 1.f;
    }
    atomicAdd(&pooled[(size_t)g * DOUT_DIM + c], s);
    if (c == 0) atomicAdd(&cnt[g], cn);
}

__global__ __launch_bounds__(256)
void finalize_kernel(const float* __restrict__ pooled, const float* __restrict__ cnt,
                     float* __restrict__ out)
{
    int i = blockIdx.x * 256 + threadIdx.x;
    if (i >= N_GRAPH * DOUT_DIM) return;
    out[i] = pooled[i] / fmaxf(cnt[i / DOUT_DIM], 1.f);
}

// ---------------------------------------------------------------------------
extern "C" void kernel_launch(void* const* d_in, const int* in_sizes, int n_in,
                              void* d_out, int out_size, void* d_ws, size_t ws_size,
                              hipStream_t stream)
{
    const float* x      = (const float*)d_in[0];
    const float* ea     = (const float*)d_in[1];
    const int*   eidx   = (const int*)d_in[2];
    const int*   batch  = (const int*)d_in[3];
    const float* W_src  = (const float*)d_in[4];
    const float* W_edge = (const float*)d_in[5];
    const float* W_dst  = (const float*)d_in[6];
    const float* W1     = (const float*)d_in[7];
    const float* b1     = (const float*)d_in[8];
    const float* g1     = (const float*)d_in[9];
    const float* be1    = (const float*)d_in[10];
    const float* W2     = (const float*)d_in[11];
    const float* b2     = (const float*)d_in[12];
    const float* g2     = (const float*)d_in[13];
    const float* be2    = (const float*)d_in[14];
    const float* W3     = (const float*)d_in[15];
    const float* b3     = (const float*)d_in[16];
    const float* L1     = (const float*)d_in[17];
    const float* bl1    = (const float*)d_in[18];
    const float* L2     = (const float*)d_in[19];
    const float* bl2    = (const float*)d_in[20];
    float* out = (float*)d_out;
    char* ws = (char*)d_ws;

    // Workspace overlay (peak ~87.9 MB; known-good region)
    f16*   ws_h     = (f16*)  (ws + 0);           // [N,304] f16, gemm_sd->agg
    f16*   ws_b2b   = (f16*)  (ws + 0);           // [N,608] f16, gemm2->gemm3
    float* ws_out3  = (float*)(ws + 0);           // [N,128] f32, gemm5->pool
    f16*   ws_eaf   = (f16*)  (ws + 24320000);    // [E,32] f16, gather->agg
    f16*   ws_b1b   = (f16*)  (ws + 24320000);    // [N,608] f16, gemm1->gemm2
    f16*   ws_out1b = (f16*)  (ws + 24320000);    // [N,320] f16, gemm3->gemm4
    f16*   ws_out2b = (f16*)  (ws + 37120000);    // [N,256] f16, gemm4->gemm5
    f16*   ws_out0b = (f16*)  (ws + 65280000);    // [N,320] f16, gemm_sd->gemm1
    f16*   ws_xb    = (f16*)  (ws + 78080000);    // [N,128] f16
    f16*   ws_wtsd  = (f16*)  (ws + 83200000);
    f16*   ws_wt1   = (f16*)  (ws + 83353600);
    f16*   ws_wt2   = (f16*)  (ws + 83737600);
    f16*   ws_wt3   = (f16*)  (ws + 84467200);
    f16*   ws_wtl1  = (f16*)  (ws + 84832000);
    f16*   ws_wtl2  = (f16*)  (ws + 84995840);
    f16*   ws_wet   = (f16*)  (ws + 85061376);    // [304,32] f16
    int*   ws_cnts  = (int*)  (ws + 85080832);
    int*   ws_curs  = (int*)  (ws + 85160832);
    int*   ws_rptr  = (int*)  (ws + 85240832);    // [20001]
    int*   ws_perm  = (int*)  (ws + 85320848);    // [E]
    int*   ws_srcs  = (int*)  (ws + 86600848);    // [E]
    float* ws_pool  = (float*)(ws + 87880848);    // [64,128]
    float* ws_cnt   = (float*)(ws + 87913616);    // [64]
    int*   ws_bsum  = (int*)  (ws + 87913872);    // [128]
    int*   ws_boffs = (int*)  (ws + 87914384);    // [128]

    hipMemsetAsync(ws_cnts, 0, N_NODES * sizeof(int), stream);
    hipMemsetAsync(ws_curs, 0, N_NODES * sizeof(int), stream);
    hipMemsetAsync(ws_pool, 0, (size_t)N_GRAPH * DOUT_DIM * 4 + N_GRAPH * 4, stream);

    dim3 blk(256);

    // casts
    cast_x<<<(N_NODES * F_IN / 4 + 255) / 256, blk, 0, stream>>>(x, ws_xb);
    {
        int total = 600*128 + 600*320 + 600*608 + 300*608 + 256*320 + 128*256 + 304*32;
        cast_weights<<<(total + 255) / 256, blk, 0, stream>>>(
            W_src, W_dst, W1, W2, W3, L1, L2, W_edge,
            ws_wtsd, ws_wt1, ws_wt2, ws_wt3, ws_wtl1, ws_wtl2, ws_wet);
    }

    // h | xd  = x @ [W_src ; W_dst]   (h -> f16 [N,304]; xd -> out0b f16)
    hgemm<false, false, false, 2><<<dim3(10, 313), blk, 0, stream>>>(
        ws_xb, ws_wtsd, nullptr, nullptr, nullptr, ws_h, ws_out0b,
        N_NODES, 600, 128, 304, 608);

    // CSR build + gather
    hist_kernel<<<512, blk, 0, stream>>>(eidx, ws_cnts);
    {
        int nb = (N_NODES + 255) / 256;   // 79
        scan1_kernel<<<nb, blk, 0, stream>>>(ws_cnts, ws_rptr, ws_bsum);
        scan2_kernel<<<1, dim3(128), 0, stream>>>(ws_bsum, ws_boffs, nb);
        scan3_kernel<<<nb, blk, 0, stream>>>(ws_rptr, ws_boffs);
    }
    scatter_kernel<<<512, blk, 0, stream>>>(eidx, ws_rptr, ws_curs, ws_perm);
    gather_kernel<<<(N_EDGES * 8 + 255) / 256, blk, 0, stream>>>(
        ea, eidx, ws_perm, ws_eaf, ws_srcs);

    // fused MFMA aggregation (out0b = softmax_agg + xd, RMW)
    agg_mfma<<<N_NODES / NPB, dim3(320), 0, stream>>>(
        ws_h, ws_eaf, ws_srcs, ws_rptr, ws_wet, ws_out0b);

    // MLP + encoder chain (f16 MFMA, fp32 accum)
    hgemm<true, true, true, 1><<<dim3(10, 313), blk, 0, stream>>>(
        ws_out0b, ws_wt1, b1, g1, be1, ws_b1b, nullptr,
        N_NODES, 600, 320, 608, 608);
    hgemm<true, true, true, 1><<<dim3(10, 313), blk, 0, stream>>>(
        ws_b1b, ws_wt2, b2, g2, be2, ws_b2b, nullptr,
        N_NODES, 600, 608, 608, 608);
    hgemm<true, false, false, 1><<<dim3(5, 313), blk, 0, stream>>>(
        ws_b2b, ws_wt3, b3, nullptr, nullptr, ws_out1b, nullptr,
        N_NODES, 300, 608, 320, 320);
    hgemm<true, true, false, 1><<<dim3(4, 313), blk, 0, stream>>>(
        ws_out1b, ws_wtl1, bl1, nullptr, nullptr, ws_out2b, nullptr,
        N_NODES, 256, 320, 256, 256);
    hgemm<true, false, false, 0><<<dim3(2, 313), blk, 0, stream>>>(
        ws_out2b, ws_wtl2, bl2, nullptr, nullptr, ws_out3, nullptr,
        N_NODES, 128, 256, 128, 128);

    // pooling
    pool_seg<<<(N_NODES + POOL_NPB - 1) / POOL_NPB, dim3(128), 0, stream>>>(
        ws_out3, batch, ws_pool, ws_cnt);
    finalize_kernel<<<(N_GRAPH * DOUT_DIM + 255) / 256, blk, 0, stream>>>(
        ws_pool, ws_cnt, out);
}

// Round 7
// 362.015 us; speedup vs baseline: 3.7801x; 1.2949x over previous
//
#include <hip/hip_runtime.h>
#include <stdint.h>
#include <stddef.h>

// Problem constants (from reference)
#define N_NODES  20000
#define N_EDGES  320000
#define N_GRAPH  64
#define F_IN     128
#define E_DIM    32
#define H_DIM    300
#define HID_DIM  600
#define DL_DIM   256
#define DOUT_DIM 128
#define BN_INV_F 0.9999950000374997f
#define EPS_MSG  1e-7f

typedef _Float16 f16;
typedef __attribute__((ext_vector_type(8))) _Float16 f16x8;
typedef __attribute__((ext_vector_type(4))) _Float16 f16x4;
typedef __attribute__((ext_vector_type(4))) float f32x4;

// ---------------------------------------------------------------------------
// f16 MFMA GEMM: C[M,Nreal] = epi(A[M,Kpad] @ Bt[Nreal,Kpad]^T)
// OUT_MODE: 0 = f32 out; 1 = f16 out (+zero cols Nreal..npad); 2 = split
//   (cols<300 -> f16 O1 stride 304 [h]; 300..619 -> f16 O2 stride 320, col-300
//    [xd], cols 600..619 zeroed -> out0b pad cols defined).
// DUAL_A: stage va = A[..] + A2[..] (used to fuse out0 = agg + xd).
// ---------------------------------------------------------------------------
template<bool HAS_BIAS, bool RELU, bool BN, int OUT_MODE, bool DUAL_A>
__global__ __launch_bounds__(256)
void hgemm(const f16* __restrict__ A, const f16* __restrict__ A2,
           const f16* __restrict__ Bt,
           const float* __restrict__ bias, const float* __restrict__ gamma,
           const float* __restrict__ beta,
           void* __restrict__ O1, void* __restrict__ O2,
           int M, int Nreal, int Kpad, int ostride, int npad)
{
    __shared__ __align__(16) f16 As[64][40];
    __shared__ __align__(16) f16 Bs[64][40];
    const int tid  = threadIdx.x;
    const int bm   = blockIdx.y * 64;
    const int bn   = blockIdx.x * 64;
    const int wave = tid >> 6;
    const int lane = tid & 63;
    const int wm   = (wave >> 1) * 32;
    const int wn   = (wave & 1) * 32;
    const int fr   = lane & 15;
    const int kg   = lane >> 4;
    const int srow = tid >> 2;
    const int skq  = (tid & 3) * 8;

    const f32x4 z = {0.f, 0.f, 0.f, 0.f};
    f32x4 acc[2][2] = {{z, z}, {z, z}};

    const f16* Arow  = A + (size_t)(bm + srow) * Kpad + skq;
    const f16* A2row = DUAL_A ? (A2 + (size_t)(bm + srow) * Kpad + skq) : nullptr;
    const f16* Brow  = Bt + (size_t)(bn + srow) * Kpad + skq;
    const bool avalid = (bm + srow) < M;
    const bool bvalid = (bn + srow) < Nreal;
    const f16x8 zf = {(f16)0, (f16)0, (f16)0, (f16)0,
                      (f16)0, (f16)0, (f16)0, (f16)0};

    for (int k0 = 0; k0 < Kpad; k0 += 32) {
        f16x8 va = zf, vb = zf;
        if (avalid) {
            va = *(const f16x8*)(Arow + k0);
            if (DUAL_A) va += *(const f16x8*)(A2row + k0);
        }
        if (bvalid) vb = *(const f16x8*)(Brow + k0);
        *(f16x8*)&As[srow][skq] = va;
        *(f16x8*)&Bs[srow][skq] = vb;
        __syncthreads();
        f16x8 a0 = *(const f16x8*)&As[wm + fr][kg * 8];
        f16x8 a1 = *(const f16x8*)&As[wm + 16 + fr][kg * 8];
        f16x8 b0 = *(const f16x8*)&Bs[wn + fr][kg * 8];
        f16x8 b1 = *(const f16x8*)&Bs[wn + 16 + fr][kg * 8];
        acc[0][0] = __builtin_amdgcn_mfma_f32_16x16x32_f16(a0, b0, acc[0][0], 0, 0, 0);
        acc[0][1] = __builtin_amdgcn_mfma_f32_16x16x32_f16(a0, b1, acc[0][1], 0, 0, 0);
        acc[1][0] = __builtin_amdgcn_mfma_f32_16x16x32_f16(a1, b0, acc[1][0], 0, 0, 0);
        acc[1][1] = __builtin_amdgcn_mfma_f32_16x16x32_f16(a1, b1, acc[1][1], 0, 0, 0);
        __syncthreads();
    }

    #pragma unroll
    for (int mi = 0; mi < 2; ++mi) {
        #pragma unroll
        for (int r = 0; r < 4; ++r) {
            int row = bm + wm + mi * 16 + kg * 4 + r;
            if (row >= M) continue;
            #pragma unroll
            for (int ni = 0; ni < 2; ++ni) {
                int col = bn + wn + ni * 16 + fr;
                float v = acc[mi][ni][r];
                if (OUT_MODE == 2) {
                    if (col < 300)
                        ((f16*)O1)[(size_t)row * 304 + col] = (f16)v;   // h f16
                    else if (col < 600)
                        ((f16*)O2)[(size_t)row * 320 + (col - 300)] = (f16)v;
                    else if (col < 620)
                        ((f16*)O2)[(size_t)row * 320 + (col - 300)] = (f16)0.f;
                } else {
                    if (col < Nreal) {
                        if (HAS_BIAS) v += bias[col];
                        if (RELU)     v = fmaxf(v, 0.f);
                        if (BN)       v = v * (BN_INV_F * gamma[col]) + beta[col];
                        if (OUT_MODE == 0)
                            ((float*)O1)[(size_t)row * ostride + col] = v;
                        else
                            ((f16*)O1)[(size_t)row * ostride + col] = (f16)v;
                    } else if (OUT_MODE == 1 && col < npad) {
                        ((f16*)O1)[(size_t)row * ostride + col] = (f16)0.f;
                    }
                }
            }
        }
    }
}

// ---------------------------------------------------------------------------
// casts
// ---------------------------------------------------------------------------
__global__ __launch_bounds__(256)
void cast_x(const float* __restrict__ x, f16* __restrict__ xb)
{
    int i = blockIdx.x * 256 + threadIdx.x;
    if (i >= N_NODES * F_IN / 4) return;
    float4 v = ((const float4*)x)[i];
    f16x4 o = {(f16)v.x, (f16)v.y, (f16)v.z, (f16)v.w};
    ((f16x4*)xb)[i] = o;
}

// Fused transpose+cast of all weights into Wt[n][Kpad] f16 (pad k zeroed).
__global__ __launch_bounds__(256)
void cast_weights(const float* __restrict__ Wsrc, const float* __restrict__ Wdst,
                  const float* __restrict__ W1, const float* __restrict__ W2,
                  const float* __restrict__ W3, const float* __restrict__ L1,
                  const float* __restrict__ L2, const float* __restrict__ We,
                  f16* __restrict__ Wt_sd, f16* __restrict__ Wt1,
                  f16* __restrict__ Wt2, f16* __restrict__ Wt3,
                  f16* __restrict__ WtL1, f16* __restrict__ WtL2,
                  f16* __restrict__ Wet)
{
    int t = blockIdx.x * 256 + threadIdx.x;
    if (t < 600 * 128) {
        int n = t / 128, k = t % 128;
        const float* W = (n < 300) ? Wsrc : Wdst;
        int nn = (n < 300) ? n : n - 300;
        Wt_sd[t] = (f16)W[(size_t)k * 300 + nn];
        return;
    }
    t -= 600 * 128;
    if (t < 600 * 320) {
        int n = t / 320, k = t % 320;
        Wt1[t] = (f16)((k < 300) ? W1[(size_t)k * 600 + n] : 0.f);
        return;
    }
    t -= 600 * 320;
    if (t < 600 * 608) {
        int n = t / 608, k = t % 608;
        Wt2[t] = (f16)((k < 600) ? W2[(size_t)k * 600 + n] : 0.f);
        return;
    }
    t -= 600 * 608;
    if (t < 300 * 608) {
        int n = t / 608, k = t % 608;
        Wt3[t] = (f16)((k < 600) ? W3[(size_t)k * 300 + n] : 0.f);
        return;
    }
    t -= 300 * 608;
    if (t < 256 * 320) {
        int n = t / 320, k = t % 320;
        WtL1[t] = (f16)((k < 300) ? L1[(size_t)k * 256 + n] : 0.f);
        return;
    }
    t -= 256 * 320;
    if (t < 128 * 256) {
        int n = t / 256, k = t % 256;
        WtL2[t] = (f16)L2[(size_t)k * 128 + n];
        return;
    }
    t -= 128 * 256;
    if (t < 304 * 32) {                       // Wet[n][k] = We[k][n], rows 300..303 zero
        int n = t / 32, k = t % 32;
        Wet[t] = (f16)((n < 300) ? We[(size_t)k * 300 + n] : 0.f);
    }
}

// ---------------------------------------------------------------------------
// CSR build: histogram, hierarchical scan (3 kernels), scatter, gather(f16)
// ---------------------------------------------------------------------------
__global__ __launch_bounds__(256)
void hist_kernel(const int* __restrict__ ei, int* __restrict__ counts)
{
    for (int e = blockIdx.x * 256 + threadIdx.x; e < N_EDGES; e += gridDim.x * 256)
        atomicAdd(&counts[ei[N_EDGES + e]], 1);
}

__global__ __launch_bounds__(256)
void scan1_kernel(const int* __restrict__ counts, int* __restrict__ rowptr,
                  int* __restrict__ bsum)
{
    __shared__ int sd[256];
    int tid = threadIdx.x;
    int i = blockIdx.x * 256 + tid;
    int v = (i < N_NODES) ? counts[i] : 0;
    sd[tid] = v;
    __syncthreads();
    #pragma unroll
    for (int off = 1; off < 256; off <<= 1) {
        int t = (tid >= off) ? sd[tid - off] : 0;
        __syncthreads();
        sd[tid] += t;
        __syncthreads();
    }
    if (i < N_NODES) rowptr[i + 1] = sd[tid];   // block-local inclusive
    if (tid == 255) bsum[blockIdx.x] = sd[255];
}

__global__ __launch_bounds__(128)
void scan2_kernel(const int* __restrict__ bsum, int* __restrict__ boffs, int nb)
{
    __shared__ int sd[128];
    int tid = threadIdx.x;
    int v = (tid < nb) ? bsum[tid] : 0;
    sd[tid] = v;
    __syncthreads();
    #pragma unroll
    for (int off = 1; off < 128; off <<= 1) {
        int t = (tid >= off) ? sd[tid - off] : 0;
        __syncthreads();
        sd[tid] += t;
        __syncthreads();
    }
    if (tid < nb) boffs[tid] = sd[tid] - v;     // exclusive
}

__global__ __launch_bounds__(256)
void scan3_kernel(int* __restrict__ rowptr, const int* __restrict__ boffs)
{
    int i = blockIdx.x * 256 + threadIdx.x;
    if (i < N_NODES) rowptr[i + 1] += boffs[blockIdx.x];
    if (i == 0) rowptr[0] = 0;
}

__global__ __launch_bounds__(256)
void scatter_kernel(const int* __restrict__ ei, const int* __restrict__ rowptr,
                    int* __restrict__ cursor, int* __restrict__ perm)
{
    for (int e = blockIdx.x * 256 + threadIdx.x; e < N_EDGES; e += gridDim.x * 256) {
        int d = ei[N_EDGES + e];
        int pos = atomicAdd(&cursor[d], 1);
        perm[rowptr[d] + pos] = e;
    }
}

// eaf[p] = (f16)ea[perm[p]]; srcs[p] = ei_src[perm[p]]
__global__ __launch_bounds__(256)
void gather_kernel(const float* __restrict__ ea, const int* __restrict__ ei,
                   const int* __restrict__ perm, f16* __restrict__ eaf,
                   int* __restrict__ srcs)
{
    int t = blockIdx.x * 256 + threadIdx.x;
    int p = t >> 3, q = t & 7;
    if (p >= N_EDGES) return;
    int e = perm[p];
    float4 v = ((const float4*)(ea + (size_t)e * E_DIM))[q];
    f16x4 o = {(f16)v.x, (f16)v.y, (f16)v.z, (f16)v.w};
    ((f16x4*)(eaf + (size_t)p * E_DIM))[q] = o;
    if (q == 0) srcs[p] = ei[e];
}

// ---------------------------------------------------------------------------
// Fused aggregation v3: block = 320 threads (5 waves) owns NPB=10 nodes.
// launch_bounds(320,1) -> real 16-deep register prefetch (round 6's VGPR=40
// serialized every h-load: ~900 cy/edge). Walk loads are UNCONDITIONAL and
// branchless (clamped addresses; dead lanes masked at flush). Flush is a
// pure store to aggb; out0 = agg + xd is fused into gemm1 (DUAL_A).
// ---------------------------------------------------------------------------
#define NPB 10
#define CHK 32
#define ELDS_STRIDE 308

__global__ __launch_bounds__(320, 1)
void agg_mfma(const f16* __restrict__ hf, const f16* __restrict__ eaf,
              const int* __restrict__ srcs, const int* __restrict__ rptr,
              const f16* __restrict__ Wet, f16* __restrict__ aggb)
{
    __shared__ __align__(16) f16 As[CHK][40];
    __shared__ __align__(16) f16 e_lds[CHK * ELDS_STRIDE];
    __shared__ int s_lds[CHK];

    const int tid  = threadIdx.x;
    const int w    = tid >> 6;           // wave 0..4
    const int lane = tid & 63;
    const int fr   = lane & 15;
    const int kg   = lane >> 4;
    const int c    = tid;                // channel owned in accumulate phase
    const bool act = c < H_DIM;
    const int cc   = c < 304 ? c : 303;  // clamped channel for safe loads

    const int n0 = blockIdx.x * NPB;
    const int n1 = n0 + NPB;
    const int P0 = rptr[n0];
    const int P1 = rptr[n1];

    // B-fragments: wave w owns N-tiles {w, w+5, w+10, w+15} (tile<19)
    f16x8 bf0, bf1, bf2, bf3;
    {
        int t0 = w;
        bf0 = *(const f16x8*)(Wet + (size_t)(t0 * 16 + fr) * 32 + kg * 8);
        bf1 = *(const f16x8*)(Wet + (size_t)((t0 + 5) * 16 + fr) * 32 + kg * 8);
        bf2 = *(const f16x8*)(Wet + (size_t)((t0 + 10) * 16 + fr) * 32 + kg * 8);
        if (t0 + 15 < 19)
            bf3 = *(const f16x8*)(Wet + (size_t)((t0 + 15) * 16 + fr) * 32 + kg * 8);
    }

    const f32x4 z4 = {0.f, 0.f, 0.f, 0.f};

    int n_cur = n0;
    int e_end = (n_cur < n1) ? rptr[n_cur + 1] : 0x7fffffff;
    float num = 0.f, den = 0.f;

    auto flush = [&]() {
        float agg = den > 0.f ? num / den : 0.f;
        aggb[(size_t)n_cur * 320 + c] = act ? (f16)agg : (f16)0.f;
        num = 0.f; den = 0.f;
        ++n_cur;
        e_end = (n_cur < n1) ? rptr[n_cur + 1] : 0x7fffffff;
    };

    for (int ck = P0; ck < P1; ck += CHK) {
        const int cend = min(ck + CHK, P1);
        // ---- stage eaf rows + srcs for [ck, ck+32) ----
        if (tid < 128) {
            int row = tid >> 2;
            int kq  = (tid & 3) * 8;
            int p   = ck + row;
            if (p >= N_EDGES) p = N_EDGES - 1;   // clamp (garbage rows unused)
            *(f16x8*)&As[row][kq] = *(const f16x8*)(eaf + (size_t)p * E_DIM + kq);
        } else if (tid < 128 + CHK) {
            int j = tid - 128;
            int p = ck + j;
            s_lds[j] = srcs[p < N_EDGES ? p : N_EDGES - 1];
        }
        __syncthreads();
        // ---- MFMA projection: e_lds[edge][chan] = (As @ Wet^T) ----
        {
            f16x8 af0 = *(const f16x8*)&As[fr][kg * 8];
            f16x8 af1 = *(const f16x8*)&As[16 + fr][kg * 8];
            #pragma unroll
            for (int i = 0; i < 4; ++i) {
                int t = w + 5 * i;
                if (t >= 19) continue;
                f16x8 bf = (i == 0) ? bf0 : (i == 1) ? bf1 : (i == 2) ? bf2 : bf3;
                #pragma unroll
                for (int mi = 0; mi < 2; ++mi) {
                    f16x8 af = (mi == 0) ? af0 : af1;
                    f32x4 d = __builtin_amdgcn_mfma_f32_16x16x32_f16(af, bf, z4, 0, 0, 0);
                    int col = t * 16 + fr;
                    int rbase = mi * 16 + kg * 4;
                    #pragma unroll
                    for (int r = 0; r < 4; ++r)
                        e_lds[(size_t)(rbase + r) * ELDS_STRIDE + col] = (f16)d[r];
                }
            }
        }
        __syncthreads();
        // ---- walk: branchless 16-deep register prefetch, then consume ----
        for (int ck2 = ck; ck2 < cend; ck2 += 16) {
            float hv[16], ev[16];
            #pragma unroll
            for (int j = 0; j < 16; ++j) {
                int idx = (ck2 - ck) + j;               // 0..31, always staged
                int s = s_lds[idx];
                hv[j] = (float)hf[(size_t)s * 304 + cc];
                ev[j] = (float)e_lds[(size_t)idx * ELDS_STRIDE + cc];
            }
            #pragma unroll
            for (int j = 0; j < 16; ++j) {
                int p = ck2 + j;
                if (p < cend) {                          // uniform guard
                    while (p == e_end) flush();
                    float msg = fmaxf(hv[j] + ev[j], 0.f) + EPS_MSG;
                    float ex = __expf(msg);
                    den += ex;
                    num += msg * ex;
                }
            }
        }
        __syncthreads();   // e_lds/As/s_lds consumed before next chunk overwrites
    }
    // flush trailing node(s) (incl. empty nodes / zero-edge blocks)
    while (n_cur < n1) flush();
}

// ---------------------------------------------------------------------------
// segmented pooling (batch is sorted)
// ---------------------------------------------------------------------------
#define POOL_NPB 128
__global__ __launch_bounds__(128)
void pool_seg(const float* __restrict__ out3, const int* __restrict__ batch,
              float* __restrict__ pooled, float* __restrict__ cnt)
{
    int c = threadIdx.x;
    int n0 = blockIdx.x * POOL_NPB;
    int n1 = min(n0 + POOL_NPB, N_NODES);
    int g = batch[n0];
    float s = 0.f, cn = 0.f;
    for (int n = n0; n < n1; ++n) {
        int gn = batch[n];
        if (gn != g) {
            atomicAdd(&pooled[(size_t)g * DOUT_DIM + c], s);
            if (c == 0) atomicAdd(&cnt[g], cn);
            g = gn; s = 0.f; cn = 0.f;
        }
        s += out3[(size_t)n * DOUT_DIM + c];
        cn += 1.f;
    }
    atomicAdd(&pooled[(size_t)g * DOUT_DIM + c], s);
    if (c == 0) atomicAdd(&cnt[g], cn);
}

__global__ __launch_bounds__(256)
void finalize_kernel(const float* __restrict__ pooled, const float* __restrict__ cnt,
                     float* __restrict__ out)
{
    int i = blockIdx.x * 256 + threadIdx.x;
    if (i >= N_GRAPH * DOUT_DIM) return;
    out[i] = pooled[i] / fmaxf(cnt[i / DOUT_DIM], 1.f);
}

// ---------------------------------------------------------------------------
extern "C" void kernel_launch(void* const* d_in, const int* in_sizes, int n_in,
                              void* d_out, int out_size, void* d_ws, size_t ws_size,
                              hipStream_t stream)
{
    const float* x      = (const float*)d_in[0];
    const float* ea     = (const float*)d_in[1];
    const int*   eidx   = (const int*)d_in[2];
    const int*   batch  = (const int*)d_in[3];
    const float* W_src  = (const float*)d_in[4];
    const float* W_edge = (const float*)d_in[5];
    const float* W_dst  = (const float*)d_in[6];
    const float* W1     = (const float*)d_in[7];
    const float* b1     = (const float*)d_in[8];
    const float* g1     = (const float*)d_in[9];
    const float* be1    = (const float*)d_in[10];
    const float* W2     = (const float*)d_in[11];
    const float* b2     = (const float*)d_in[12];
    const float* g2     = (const float*)d_in[13];
    const float* be2    = (const float*)d_in[14];
    const float* W3     = (const float*)d_in[15];
    const float* b3     = (const float*)d_in[16];
    const float* L1     = (const float*)d_in[17];
    const float* bl1    = (const float*)d_in[18];
    const float* L2     = (const float*)d_in[19];
    const float* bl2    = (const float*)d_in[20];
    float* out = (float*)d_out;
    char* ws = (char*)d_ws;

    // Workspace overlay (peak ~87.9 MB; known-good region)
    f16*   ws_h     = (f16*)  (ws + 0);           // [N,304] f16, gemm_sd->agg
    f16*   ws_b2b   = (f16*)  (ws + 0);           // [N,608] f16, gemm2->gemm3
    float* ws_out3  = (float*)(ws + 0);           // [N,128] f32, gemm5->pool
    f16*   ws_eaf   = (f16*)  (ws + 24320000);    // [E,32] f16 (24.32M..44.8M), gather->agg
    f16*   ws_b1b   = (f16*)  (ws + 24320000);    // [N,608] f16, gemm1->gemm2
    f16*   ws_out1b = (f16*)  (ws + 24320000);    // [N,320] f16, gemm3->gemm4
    f16*   ws_out2b = (f16*)  (ws + 37120000);    // [N,256] f16, gemm4->gemm5
    f16*   ws_aggb  = (f16*)  (ws + 44800000);    // [N,320] f16 (44.8M..57.6M), agg->gemm1
    f16*   ws_out0b = (f16*)  (ws + 65280000);    // [N,320] f16 (xd), gemm_sd->gemm1
    f16*   ws_xb    = (f16*)  (ws + 78080000);    // [N,128] f16
    f16*   ws_wtsd  = (f16*)  (ws + 83200000);
    f16*   ws_wt1   = (f16*)  (ws + 83353600);
    f16*   ws_wt2   = (f16*)  (ws + 83737600);
    f16*   ws_wt3   = (f16*)  (ws + 84467200);
    f16*   ws_wtl1  = (f16*)  (ws + 84832000);
    f16*   ws_wtl2  = (f16*)  (ws + 84995840);
    f16*   ws_wet   = (f16*)  (ws + 85061376);    // [304,32] f16
    int*   ws_cnts  = (int*)  (ws + 85080832);
    int*   ws_curs  = (int*)  (ws + 85160832);
    int*   ws_rptr  = (int*)  (ws + 85240832);    // [20001]
    int*   ws_perm  = (int*)  (ws + 85320848);    // [E]
    int*   ws_srcs  = (int*)  (ws + 86600848);    // [E]
    float* ws_pool  = (float*)(ws + 87880848);    // [64,128]
    float* ws_cnt   = (float*)(ws + 87913616);    // [64]
    int*   ws_bsum  = (int*)  (ws + 87913872);    // [128]
    int*   ws_boffs = (int*)  (ws + 87914384);    // [128]

    hipMemsetAsync(ws_cnts, 0, N_NODES * sizeof(int), stream);
    hipMemsetAsync(ws_curs, 0, N_NODES * sizeof(int), stream);
    hipMemsetAsync(ws_pool, 0, (size_t)N_GRAPH * DOUT_DIM * 4 + N_GRAPH * 4, stream);

    dim3 blk(256);

    // casts
    cast_x<<<(N_NODES * F_IN / 4 + 255) / 256, blk, 0, stream>>>(x, ws_xb);
    {
        int total = 600*128 + 600*320 + 600*608 + 300*608 + 256*320 + 128*256 + 304*32;
        cast_weights<<<(total + 255) / 256, blk, 0, stream>>>(
            W_src, W_dst, W1, W2, W3, L1, L2, W_edge,
            ws_wtsd, ws_wt1, ws_wt2, ws_wt3, ws_wtl1, ws_wtl2, ws_wet);
    }

    // h | xd  = x @ [W_src ; W_dst]   (h -> f16 [N,304]; xd -> out0b f16, pads zeroed)
    hgemm<false, false, false, 2, false><<<dim3(10, 313), blk, 0, stream>>>(
        ws_xb, nullptr, ws_wtsd, nullptr, nullptr, nullptr, ws_h, ws_out0b,
        N_NODES, 600, 128, 304, 608);

    // CSR build + gather
    hist_kernel<<<512, blk, 0, stream>>>(eidx, ws_cnts);
    {
        int nb = (N_NODES + 255) / 256;   // 79
        scan1_kernel<<<nb, blk, 0, stream>>>(ws_cnts, ws_rptr, ws_bsum);
        scan2_kernel<<<1, dim3(128), 0, stream>>>(ws_bsum, ws_boffs, nb);
        scan3_kernel<<<nb, blk, 0, stream>>>(ws_rptr, ws_boffs);
    }
    scatter_kernel<<<512, blk, 0, stream>>>(eidx, ws_rptr, ws_curs, ws_perm);
    gather_kernel<<<(N_EDGES * 8 + 255) / 256, blk, 0, stream>>>(
        ea, eidx, ws_perm, ws_eaf, ws_srcs);

    // fused MFMA aggregation -> aggb (pure store; xd added in gemm1)
    agg_mfma<<<N_NODES / NPB, dim3(320), 0, stream>>>(
        ws_h, ws_eaf, ws_srcs, ws_rptr, ws_wet, ws_aggb);

    // MLP + encoder chain (f16 MFMA, fp32 accum); gemm1 stages A = aggb + xd
    hgemm<true, true, true, 1, true><<<dim3(10, 313), blk, 0, stream>>>(
        ws_aggb, ws_out0b, ws_wt1, b1, g1, be1, ws_b1b, nullptr,
        N_NODES, 600, 320, 608, 608);
    hgemm<true, true, true, 1, false><<<dim3(10, 313), blk, 0, stream>>>(
        ws_b1b, nullptr, ws_wt2, b2, g2, be2, ws_b2b, nullptr,
        N_NODES, 600, 608, 608, 608);
    hgemm<true, false, false, 1, false><<<dim3(5, 313), blk, 0, stream>>>(
        ws_b2b, nullptr, ws_wt3, b3, nullptr, nullptr, ws_out1b, nullptr,
        N_NODES, 300, 608, 320, 320);
    hgemm<true, true, false, 1, false><<<dim3(4, 313), blk, 0, stream>>>(
        ws_out1b, nullptr, ws_wtl1, bl1, nullptr, nullptr, ws_out2b, nullptr,
        N_NODES, 256, 320, 256, 256);
    hgemm<true, false, false, 0, false><<<dim3(2, 313), blk, 0, stream>>>(
        ws_out2b, nullptr, ws_wtl2, bl2, nullptr, nullptr, ws_out3, nullptr,
        N_NODES, 128, 256, 128, 128);

    // pooling
    pool_seg<<<(N_NODES + POOL_NPB - 1) / POOL_NPB, dim3(128), 0, stream>>>(
        ws_out3, batch, ws_pool, ws_cnt);
    finalize_kernel<<<(N_GRAPH * DOUT_DIM + 255) / 256, blk, 0, stream>>>(
        ws_pool, ws_cnt, out);
}